// Round 1
// baseline (3978.085 us; speedup 1.0000x reference)
//
#include <hip/hip_runtime.h>

typedef __bf16 bf16_t;
typedef __bf16 bf16x8 __attribute__((ext_vector_type(8)));
typedef __bf16 bf16x4 __attribute__((ext_vector_type(4)));
typedef float  f32x4  __attribute__((ext_vector_type(4)));

#define MFMA16(a, b, c) __builtin_amdgcn_mfma_f32_16x16x32_bf16((a), (b), (c), 0, 0, 0)

// ---------------------------------------------------------------------------
// Weight prep: W [Kact,128] f32 (row-major) -> bf16 swizzled into the MFMA
// B-fragment-sequential layout: idx = ((kc*8 + ctile)*64 + lane)*8 + j
//   n = ctile*16 + (lane&15), k = kc*32 + (lane>>4)*8 + j, zero-pad k>=Kact.
// ---------------------------------------------------------------------------
__global__ void prep_w_kernel(const float* __restrict__ W, bf16_t* __restrict__ Ws,
                              int Kact, int KP) {
    int idx = blockIdx.x * 256 + threadIdx.x;
    if (idx >= 128 * KP) return;
    int j    = idx & 7;
    int lane = (idx >> 3) & 63;
    int ct   = (idx >> 9) & 7;
    int kc   = idx >> 12;
    int n = ct * 16 + (lane & 15);
    int k = kc * 32 + (lane >> 4) * 8 + j;
    Ws[idx] = (bf16_t)((k < Kact) ? W[k * 128 + n] : 0.0f);
}

// ---------------------------------------------------------------------------
// Generic single-GEMM: out[M,128] = act(A[M,Kact] @ W + bias)
// A is f32 (converted to bf16 during LDS staging) or bf16 (stride = KP).
// Optional: dual f32 store (out2), per-channel sum/sumsq accumulation (BN).
// 128 rows/block, 256 threads (4 waves x 32 rows), 16x16x32 bf16 MFMA.
// ---------------------------------------------------------------------------
template <int KP>
__global__ __launch_bounds__(256) void gemm_kernel(
    const void* Ap, int a_is_f32, int M, int Kact,
    const bf16_t* __restrict__ Ws, const float* __restrict__ bias,
    int do_relu, void* outp, int out_bf16, float* out2, float* bn_sums)
{
    constexpr int S1 = KP + 8;  // padded LDS row stride (keeps 16B alignment)
    __shared__ bf16_t Als[128 * S1];
    __shared__ float  bls[128];
    __shared__ float  bsum[128];
    __shared__ float  bsq[128];

    const int  tid  = threadIdx.x;
    const long row0 = (long)blockIdx.x * 128;

    if (tid < 128) { bls[tid] = bias[tid]; bsum[tid] = 0.f; bsq[tid] = 0.f; }

    if (a_is_f32) {
        const float* A = (const float*)Ap;
        constexpr int U = KP / 4;
        for (int i = tid; i < 128 * U; i += 256) {
            int r = i / U, c4 = (i % U) * 4;
            long gr = row0 + r;
            float4 v = make_float4(0.f, 0.f, 0.f, 0.f);
            if (gr < M && c4 < Kact) v = *(const float4*)(A + gr * Kact + c4);
            bf16_t* d = &Als[r * S1 + c4];
            d[0] = (bf16_t)v.x; d[1] = (bf16_t)v.y; d[2] = (bf16_t)v.z; d[3] = (bf16_t)v.w;
        }
    } else {
        const bf16_t* A = (const bf16_t*)Ap;  // row stride == KP
        constexpr int U = KP / 8;
        for (int i = tid; i < 128 * U; i += 256) {
            int r = i / U, c8 = (i % U) * 8;
            long gr = row0 + r;
            uint4 v = make_uint4(0u, 0u, 0u, 0u);
            if (gr < M) v = *(const uint4*)(A + gr * KP + c8);
            *(uint4*)&Als[r * S1 + c8] = v;
        }
    }
    __syncthreads();

    const int wv = tid >> 6, lane = tid & 63;
    const int l16 = lane & 15, quad = lane >> 4;

    f32x4 acc[2][8];
#pragma unroll
    for (int r = 0; r < 2; r++)
#pragma unroll
        for (int c = 0; c < 8; c++) acc[r][c] = (f32x4){0.f, 0.f, 0.f, 0.f};

#pragma unroll
    for (int kc = 0; kc < KP / 32; ++kc) {
        bf16x8 af0 = *(const bf16x8*)&Als[(wv * 32 + l16) * S1 + kc * 32 + quad * 8];
        bf16x8 af1 = *(const bf16x8*)&Als[(wv * 32 + 16 + l16) * S1 + kc * 32 + quad * 8];
#pragma unroll
        for (int c = 0; c < 8; c++) {
            bf16x8 bfr = *(const bf16x8*)&Ws[(((kc * 8 + c) * 64) + lane) * 8];
            acc[0][c] = MFMA16(af0, bfr, acc[0][c]);
            acc[1][c] = MFMA16(af1, bfr, acc[1][c]);
        }
    }

#pragma unroll
    for (int r = 0; r < 2; r++) {
        int mrow = wv * 32 + r * 16 + quad * 4;
#pragma unroll
        for (int c = 0; c < 8; c++) {
            int col = c * 16 + l16;
            float bb = bls[col];
#pragma unroll
            for (int q = 0; q < 4; q++) {
                long grow = row0 + mrow + q;
                if (grow < M) {
                    float v = acc[r][c][q] + bb;
                    if (do_relu) v = fmaxf(v, 0.f);
                    if (out_bf16) ((bf16_t*)outp)[grow * 128 + col] = (bf16_t)v;
                    else          ((float*)outp)[grow * 128 + col] = v;
                    if (out2) out2[grow * 128 + col] = v;
                    if (bn_sums) { atomicAdd(&bsum[col], v); atomicAdd(&bsq[col], v * v); }
                }
            }
        }
    }
    if (bn_sums) {
        __syncthreads();
        if (tid < 128) {
            atomicAdd(&bn_sums[tid], bsum[tid]);
            atomicAdd(&bn_sums[128 + tid], bsq[tid]);
        }
    }
}

// ---------------------------------------------------------------------------
// Fused edge encoder: e = (relu(ea @ W1 + b1)) @ W2 + b2, out bf16.
// ea [E,16] f32; hidden kept in LDS (bf16); W frags read from swizzled global.
// ---------------------------------------------------------------------------
__global__ __launch_bounds__(256) void edge_mlp_kernel(
    const float* __restrict__ A, int M,
    const bf16_t* __restrict__ Ws1, const float* __restrict__ b1,
    const bf16_t* __restrict__ Ws2, const float* __restrict__ b2,
    bf16_t* __restrict__ outp)
{
    constexpr int S1 = 40, S2 = 136;
    __shared__ bf16_t Als[128 * S1];   // 10.2 KB (KP=32, Kact=16 zero-padded)
    __shared__ bf16_t Hls[128 * S2];   // 34.8 KB
    __shared__ float  bls1[128], bls2[128];

    const int  tid  = threadIdx.x;
    const long row0 = (long)blockIdx.x * 128;

    if (tid < 128) { bls1[tid] = b1[tid]; bls2[tid] = b2[tid]; }

    // stage A: 128 rows x 16 real cols (pad to 32)
    for (int i = tid; i < 128 * 8; i += 256) {
        int r = i / 8, c4 = (i % 8) * 4;
        long gr = row0 + r;
        float4 v = make_float4(0.f, 0.f, 0.f, 0.f);
        if (gr < M && c4 < 16) v = *(const float4*)(A + gr * 16 + c4);
        bf16_t* d = &Als[r * S1 + c4];
        d[0] = (bf16_t)v.x; d[1] = (bf16_t)v.y; d[2] = (bf16_t)v.z; d[3] = (bf16_t)v.w;
    }
    __syncthreads();

    const int wv = tid >> 6, lane = tid & 63;
    const int l16 = lane & 15, quad = lane >> 4;

    f32x4 acc[2][8];
#pragma unroll
    for (int r = 0; r < 2; r++)
#pragma unroll
        for (int c = 0; c < 8; c++) acc[r][c] = (f32x4){0.f, 0.f, 0.f, 0.f};

    {   // stage 1: K=32 (one chunk)
        bf16x8 af0 = *(const bf16x8*)&Als[(wv * 32 + l16) * S1 + quad * 8];
        bf16x8 af1 = *(const bf16x8*)&Als[(wv * 32 + 16 + l16) * S1 + quad * 8];
#pragma unroll
        for (int c = 0; c < 8; c++) {
            bf16x8 bfr = *(const bf16x8*)&Ws1[((c * 64) + lane) * 8];
            acc[0][c] = MFMA16(af0, bfr, acc[0][c]);
            acc[1][c] = MFMA16(af1, bfr, acc[1][c]);
        }
    }
    // hidden = relu(acc + b1) -> LDS (bf16), C/D layout positions
#pragma unroll
    for (int r = 0; r < 2; r++) {
        int mrow = wv * 32 + r * 16 + quad * 4;
#pragma unroll
        for (int c = 0; c < 8; c++) {
            int col = c * 16 + l16;
            float bb = bls1[col];
#pragma unroll
            for (int q = 0; q < 4; q++) {
                float v = fmaxf(acc[r][c][q] + bb, 0.f);
                Hls[(mrow + q) * S2 + col] = (bf16_t)v;
            }
        }
    }
    __syncthreads();

#pragma unroll
    for (int r = 0; r < 2; r++)
#pragma unroll
        for (int c = 0; c < 8; c++) acc[r][c] = (f32x4){0.f, 0.f, 0.f, 0.f};

#pragma unroll
    for (int kc = 0; kc < 4; ++kc) {  // stage 2: K=128
        bf16x8 af0 = *(const bf16x8*)&Hls[(wv * 32 + l16) * S2 + kc * 32 + quad * 8];
        bf16x8 af1 = *(const bf16x8*)&Hls[(wv * 32 + 16 + l16) * S2 + kc * 32 + quad * 8];
#pragma unroll
        for (int c = 0; c < 8; c++) {
            bf16x8 bfr = *(const bf16x8*)&Ws2[(((kc * 8 + c) * 64) + lane) * 8];
            acc[0][c] = MFMA16(af0, bfr, acc[0][c]);
            acc[1][c] = MFMA16(af1, bfr, acc[1][c]);
        }
    }
#pragma unroll
    for (int r = 0; r < 2; r++) {
        int mrow = wv * 32 + r * 16 + quad * 4;
#pragma unroll
        for (int c = 0; c < 8; c++) {
            int col = c * 16 + l16;
            float bb = bls2[col];
#pragma unroll
            for (int q = 0; q < 4; q++) {
                long grow = row0 + mrow + q;
                if (grow < M) outp[grow * 128 + col] = (bf16_t)(acc[r][c][q] + bb);
            }
        }
    }
}

// ---------------------------------------------------------------------------
// GINE message + scatter: aggr[dst] += relu(h[src] + e)   (aggr pre-init to h)
// 32 threads/edge x 4 channels each.
// ---------------------------------------------------------------------------
__global__ __launch_bounds__(256) void msg_kernel(
    const float* __restrict__ h, const bf16_t* __restrict__ e,
    const int* __restrict__ ei, float* __restrict__ aggr, int E)
{
    long t = (long)blockIdx.x * 256 + threadIdx.x;
    long edge = t >> 5;
    if (edge >= E) return;
    int c0 = (int)(t & 31) * 4;
    int s = ei[edge];
    int d = ei[(long)E + edge];
    float4 hv = *(const float4*)(h + (long)s * 128 + c0);
    bf16x4 ev = *(const bf16x4*)(e + edge * 128 + c0);
    float m0 = fmaxf(hv.x + (float)ev[0], 0.f);
    float m1 = fmaxf(hv.y + (float)ev[1], 0.f);
    float m2 = fmaxf(hv.z + (float)ev[2], 0.f);
    float m3 = fmaxf(hv.w + (float)ev[3], 0.f);
    float* ap = aggr + (long)d * 128 + c0;
    atomicAdd(ap + 0, m0);
    atomicAdd(ap + 1, m1);
    atomicAdd(ap + 2, m2);
    atomicAdd(ap + 3, m3);
}

// ---------------------------------------------------------------------------
// BN finalize: scale/shift per channel from accumulated sum/sumsq.
// ---------------------------------------------------------------------------
__global__ void bn_fin_kernel(const float* __restrict__ sums, const float* __restrict__ gamma,
                              const float* __restrict__ beta, float* __restrict__ scsh, int N)
{
    int c = threadIdx.x;
    float mean = sums[c] / (float)N;
    float var  = sums[128 + c] / (float)N - mean * mean;
    float inv  = rsqrtf(var + 1e-5f);
    float sc   = gamma[c] * inv;
    scsh[c]       = sc;
    scsh[128 + c] = beta[c] - mean * sc;
}

// BN apply + relu; optionally dual-store into aggr (next layer's init). In-place safe.
__global__ __launch_bounds__(256) void bn_apply_kernel(
    const float* z, const float* scsh, float* h, float* aggr, long total)
{
    long idx = (long)blockIdx.x * 256 + threadIdx.x;
    if (idx >= total) return;
    int c = (int)(idx & 127);
    float v = fmaxf(z[idx] * scsh[c] + scsh[128 + c], 0.f);
    h[idx] = v;
    if (aggr) aggr[idx] = v;
}

// ---------------------------------------------------------------------------
// Mean-pool over sorted batch: run-length accumulate in registers, flush on
// graph change. 128 threads (one per channel), 256 nodes per block.
// ---------------------------------------------------------------------------
__global__ __launch_bounds__(128) void pool_kernel(
    const float* __restrict__ h, const int* __restrict__ batch,
    float* __restrict__ gsum, float* __restrict__ cnt, int N)
{
    int c = threadIdx.x;
    int n0 = blockIdx.x * 256;
    int n1 = min(n0 + 256, N);
    float acc = 0.f;
    int cur = -1, rc = 0;
    for (int n = n0; n < n1; ++n) {
        int g = batch[n];
        if (g != cur) {
            if (cur >= 0) {
                atomicAdd(&gsum[(long)cur * 128 + c], acc);
                if (c == 0) atomicAdd(&cnt[cur], (float)rc);
            }
            cur = g; acc = 0.f; rc = 0;
        }
        acc += h[(long)n * 128 + c];
        rc++;
    }
    if (cur >= 0) {
        atomicAdd(&gsum[(long)cur * 128 + c], acc);
        if (c == 0) atomicAdd(&cnt[cur], (float)rc);
    }
}

// ---------------------------------------------------------------------------
// Head: ext MLP + concat + regressor, one block per graph, fp32 vector.
// ---------------------------------------------------------------------------
__global__ __launch_bounds__(128) void head_kernel(
    const float* __restrict__ gsum, const float* __restrict__ cnt,
    const float* __restrict__ ext_in,
    const float* __restrict__ ew1, const float* __restrict__ eb1,
    const float* __restrict__ ew2, const float* __restrict__ eb2,
    const float* __restrict__ rw1, const float* __restrict__ rb1,
    const float* __restrict__ rw2, const float* __restrict__ rb2,
    float* __restrict__ out)
{
    int g = blockIdx.x, c = threadIdx.x;
    __shared__ float sx[8];
    __shared__ float h1[128];
    __shared__ float comb[256];
    __shared__ float red[128];

    if (c < 8) sx[c] = ext_in[g * 8 + c];
    __syncthreads();
    float a = eb1[c];
#pragma unroll
    for (int k = 0; k < 8; k++) a += sx[k] * ew1[k * 128 + c];
    h1[c] = fmaxf(a, 0.f);
    __syncthreads();
    float b = eb2[c];
    for (int k = 0; k < 128; k++) b += h1[k] * ew2[k * 128 + c];
    comb[c]       = gsum[(long)g * 128 + c] / fmaxf(cnt[g], 1.0f);
    comb[128 + c] = b;
    __syncthreads();
    float r = rb1[c];
    for (int k = 0; k < 256; k++) r += comb[k] * rw1[k * 128 + c];
    r = fmaxf(r, 0.f);
    red[c] = r * rw2[c];
    __syncthreads();
    if (c == 0) {
        float s = rb2[0];
        for (int k = 0; k < 128; k++) s += red[k];
        out[g] = s;
    }
}

// ---------------------------------------------------------------------------
extern "C" void kernel_launch(void* const* d_in, const int* in_sizes, int n_in,
                              void* d_out, int out_size, void* d_ws, size_t ws_size,
                              hipStream_t stream)
{
    const float* x         = (const float*)d_in[0];
    const float* edge_attr = (const float*)d_in[1];
    const float* externals = (const float*)d_in[2];
    const float* node_w    = (const float*)d_in[3];
    const float* node_b    = (const float*)d_in[4];
    const float* ee_w1     = (const float*)d_in[5];
    const float* ee_b1     = (const float*)d_in[6];
    const float* ee_w2     = (const float*)d_in[7];
    const float* ee_b2     = (const float*)d_in[8];
    const float* conv_w1   = (const float*)d_in[9];
    const float* conv_b1   = (const float*)d_in[10];
    const float* conv_w2   = (const float*)d_in[11];
    const float* conv_b2   = (const float*)d_in[12];
    const float* bn_gamma  = (const float*)d_in[13];
    const float* bn_beta   = (const float*)d_in[14];
    const float* ext_w1    = (const float*)d_in[15];
    const float* ext_b1    = (const float*)d_in[16];
    const float* ext_w2    = (const float*)d_in[17];
    const float* ext_b2    = (const float*)d_in[18];
    const float* reg_w1    = (const float*)d_in[19];
    const float* reg_b1    = (const float*)d_in[20];
    const float* reg_w2    = (const float*)d_in[21];
    const float* reg_b2    = (const float*)d_in[22];
    const int* edge_index  = (const int*)d_in[23];
    const int* batch       = (const int*)d_in[24];

    const int N = in_sizes[0] / 32;
    const int E = in_sizes[1] / 16;
    const int G = in_sizes[2] / 8;

    char* p = (char*)d_ws;
    auto alloc = [&](size_t bytes) -> void* {
        void* r = (void*)p;
        p += (bytes + 255) & ~(size_t)255;
        return r;
    };
    float*  h       = (float*)alloc((size_t)N * 128 * sizeof(float));
    float*  aggr    = (float*)alloc((size_t)N * 128 * sizeof(float));   // also z2
    bf16_t* tbuf    = (bf16_t*)alloc((size_t)N * 128 * sizeof(bf16_t)); // conv hidden
    bf16_t* ebuf    = (bf16_t*)alloc((size_t)E * 128 * sizeof(bf16_t));
    bf16_t* node_wt = (bf16_t*)alloc(128 * 32 * 2);
    bf16_t* ee_w1t  = (bf16_t*)alloc(128 * 32 * 2);
    bf16_t* ee_w2t  = (bf16_t*)alloc(128 * 128 * 2);
    bf16_t* cw1t    = (bf16_t*)alloc(3 * 128 * 128 * 2);
    bf16_t* cw2t    = (bf16_t*)alloc(3 * 128 * 128 * 2);
    float*  bn_sums = (float*)alloc(256 * 4);
    float*  scsh    = (float*)alloc(256 * 4);
    float*  gsum    = (float*)alloc((size_t)G * 128 * 4);
    float*  cnt     = (float*)alloc((size_t)G * 4);

    // --- weight prep (bf16, MFMA-B-fragment swizzled) ---
    prep_w_kernel<<<16, 256, 0, stream>>>(node_w, node_wt, 32, 32);
    prep_w_kernel<<<16, 256, 0, stream>>>(ee_w1, ee_w1t, 16, 32);
    prep_w_kernel<<<64, 256, 0, stream>>>(ee_w2, ee_w2t, 128, 128);
    for (int l = 0; l < 3; l++) {
        prep_w_kernel<<<64, 256, 0, stream>>>(conv_w1 + l * 16384, cw1t + l * 16384, 128, 128);
        prep_w_kernel<<<64, 256, 0, stream>>>(conv_w2 + l * 16384, cw2t + l * 16384, 128, 128);
    }

    // --- node encoder: h = x @ node_w + node_b ; aggr = h ---
    gemm_kernel<32><<<(N + 127) / 128, 256, 0, stream>>>(
        x, 1, N, 32, node_wt, node_b, 0, h, 0, aggr, nullptr);

    // --- edge encoder (fused 2-layer MLP) -> e (bf16) ---
    edge_mlp_kernel<<<(E + 127) / 128, 256, 0, stream>>>(
        edge_attr, E, ee_w1t, ee_b1, ee_w2t, ee_b2, ebuf);

    // --- GINE layers ---
    for (int l = 0; l < 3; l++) {
        msg_kernel<<<(E * 32 + 255) / 256, 256, 0, stream>>>(h, ebuf, edge_index, aggr, E);
        hipMemsetAsync(bn_sums, 0, 256 * 4, stream);
        gemm_kernel<128><<<(N + 127) / 128, 256, 0, stream>>>(
            aggr, 1, N, 128, cw1t + l * 16384, conv_b1 + l * 128, 1, tbuf, 1, nullptr, nullptr);
        gemm_kernel<128><<<(N + 127) / 128, 256, 0, stream>>>(
            tbuf, 0, N, 128, cw2t + l * 16384, conv_b2 + l * 128, 0, aggr, 0, nullptr, bn_sums);
        bn_fin_kernel<<<1, 128, 0, stream>>>(bn_sums, bn_gamma + l * 128, bn_beta + l * 128, scsh, N);
        bn_apply_kernel<<<(int)(((long)N * 128 + 255) / 256), 256, 0, stream>>>(
            aggr, scsh, h, (l < 2) ? aggr : nullptr, (long)N * 128);
    }

    // --- pooling + head ---
    hipMemsetAsync(gsum, 0, (size_t)G * 128 * 4, stream);
    hipMemsetAsync(cnt, 0, (size_t)G * 4, stream);
    pool_kernel<<<(N + 255) / 256, 128, 0, stream>>>(h, batch, gsum, cnt, N);
    head_kernel<<<G, 128, 0, stream>>>(gsum, cnt, externals,
                                       ext_w1, ext_b1, ext_w2, ext_b2,
                                       reg_w1, reg_b1, reg_w2, reg_b2,
                                       (float*)d_out);
}

// Round 2
// 1111.354 us; speedup vs baseline: 3.5795x; 3.5795x over previous
//
#include <hip/hip_runtime.h>

typedef __bf16 bf16_t;
typedef __bf16 bf16x8 __attribute__((ext_vector_type(8)));
typedef __bf16 bf16x4 __attribute__((ext_vector_type(4)));
typedef __bf16 bf16x2 __attribute__((ext_vector_type(2)));
typedef float  f32x4  __attribute__((ext_vector_type(4)));

#define MFMA16(a, b, c) __builtin_amdgcn_mfma_f32_16x16x32_bf16((a), (b), (c), 0, 0, 0)

// ---------------------------------------------------------------------------
// Weight prep: W [Kact,128] f32 row-major -> bf16 MFMA-B-fragment-sequential:
// idx = ((kc*8 + ctile)*64 + lane)*8 + j ; n = ctile*16+(lane&15),
// k = kc*32+(lane>>4)*8+j, zero-pad k>=Kact.
// ---------------------------------------------------------------------------
__global__ void prep_w_kernel(const float* __restrict__ W, bf16_t* __restrict__ Ws,
                              int Kact, int KP) {
    int idx = blockIdx.x * 256 + threadIdx.x;
    if (idx >= 128 * KP) return;
    int j    = idx & 7;
    int lane = (idx >> 3) & 63;
    int ct   = (idx >> 9) & 7;
    int kc   = idx >> 12;
    int n = ct * 16 + (lane & 15);
    int k = kc * 32 + (lane >> 4) * 8 + j;
    Ws[idx] = (bf16_t)((k < Kact) ? W[k * 128 + n] : 0.0f);
}

// ---------------------------------------------------------------------------
// CSR build: histogram of dst -> prefix scan -> scatter permutation.
// ---------------------------------------------------------------------------
__global__ __launch_bounds__(256) void hist_kernel(const int* __restrict__ ei,
                                                   int* __restrict__ deg, int E) {
    int t = blockIdx.x * 256 + threadIdx.x;
    if (t < E) atomicAdd(&deg[ei[(long)E + t]], 1);
}

// single-block exclusive scan over deg[N] -> rowptr[N+1] (+ cursor copy)
__global__ __launch_bounds__(1024) void scan_kernel(const int* __restrict__ deg,
                                                    int* __restrict__ rowptr,
                                                    int* __restrict__ cursor, int N) {
    __shared__ int part[1024];
    int t = threadIdx.x;
    int chunk = (N + 1023) >> 10;
    int b = t * chunk, e = min(b + chunk, N);
    int s = 0;
    for (int i = b; i < e; i++) s += deg[i];
    part[t] = s;
    __syncthreads();
    for (int off = 1; off < 1024; off <<= 1) {
        int v = (t >= off) ? part[t - off] : 0;
        __syncthreads();
        part[t] += v;
        __syncthreads();
    }
    int pre = (t == 0) ? 0 : part[t - 1];
    for (int i = b; i < e; i++) {
        rowptr[i] = pre;
        cursor[i] = pre;
        pre += deg[i];
    }
    if (e == N) rowptr[N] = pre;
}

__global__ __launch_bounds__(256) void scatter_kernel(const int* __restrict__ ei,
                                                      int* __restrict__ cursor,
                                                      int* __restrict__ srcp,
                                                      int* __restrict__ rank, int E) {
    int t = blockIdx.x * 256 + threadIdx.x;
    if (t >= E) return;
    int d = ei[(long)E + t];
    int pos = atomicAdd(&cursor[d], 1);
    srcp[pos] = ei[t];
    rank[t] = pos;
}

// ---------------------------------------------------------------------------
// Generic single-GEMM: out[M,128] = act(A[M,Kact] @ W + bias)
// A f32 (cast->bf16 while staging) or bf16 (stride KP). Optional BN sums.
// 128 rows/block, 256 threads, 16x16x32 bf16 MFMA, B-frags from global.
// ---------------------------------------------------------------------------
template <int KP>
__global__ __launch_bounds__(256) void gemm_kernel(
    const void* Ap, int a_is_f32, int M, int Kact,
    const bf16_t* __restrict__ Ws, const float* __restrict__ bias,
    int do_relu, void* outp, int out_bf16, float* bn_sums)
{
    constexpr int S1 = KP + 8;
    __shared__ bf16_t Als[128 * S1];
    __shared__ float  bls[128];
    __shared__ float  bsum[128];
    __shared__ float  bsq[128];

    const int  tid  = threadIdx.x;
    const long row0 = (long)blockIdx.x * 128;

    if (tid < 128) { bls[tid] = bias[tid]; bsum[tid] = 0.f; bsq[tid] = 0.f; }

    if (a_is_f32) {
        const float* A = (const float*)Ap;
        constexpr int U = KP / 4;
        for (int i = tid; i < 128 * U; i += 256) {
            int r = i / U, c4 = (i % U) * 4;
            long gr = row0 + r;
            float4 v = make_float4(0.f, 0.f, 0.f, 0.f);
            if (gr < M && c4 < Kact) v = *(const float4*)(A + gr * Kact + c4);
            bf16_t* d = &Als[r * S1 + c4];
            d[0] = (bf16_t)v.x; d[1] = (bf16_t)v.y; d[2] = (bf16_t)v.z; d[3] = (bf16_t)v.w;
        }
    } else {
        const bf16_t* A = (const bf16_t*)Ap;
        constexpr int U = KP / 8;
        for (int i = tid; i < 128 * U; i += 256) {
            int r = i / U, c8 = (i % U) * 8;
            long gr = row0 + r;
            uint4 v = make_uint4(0u, 0u, 0u, 0u);
            if (gr < M) v = *(const uint4*)(A + gr * KP + c8);
            *(uint4*)&Als[r * S1 + c8] = v;
        }
    }
    __syncthreads();

    const int wv = tid >> 6, lane = tid & 63;
    const int l16 = lane & 15, quad = lane >> 4;

    f32x4 acc[2][8];
#pragma unroll
    for (int r = 0; r < 2; r++)
#pragma unroll
        for (int c = 0; c < 8; c++) acc[r][c] = (f32x4){0.f, 0.f, 0.f, 0.f};

#pragma unroll
    for (int kc = 0; kc < KP / 32; ++kc) {
        bf16x8 af0 = *(const bf16x8*)&Als[(wv * 32 + l16) * S1 + kc * 32 + quad * 8];
        bf16x8 af1 = *(const bf16x8*)&Als[(wv * 32 + 16 + l16) * S1 + kc * 32 + quad * 8];
#pragma unroll
        for (int c = 0; c < 8; c++) {
            bf16x8 bfr = *(const bf16x8*)&Ws[(((kc * 8 + c) * 64) + lane) * 8];
            acc[0][c] = MFMA16(af0, bfr, acc[0][c]);
            acc[1][c] = MFMA16(af1, bfr, acc[1][c]);
        }
    }

#pragma unroll
    for (int r = 0; r < 2; r++) {
        int mrow = wv * 32 + r * 16 + quad * 4;
#pragma unroll
        for (int c = 0; c < 8; c++) {
            int col = c * 16 + l16;
            float bb = bls[col];
#pragma unroll
            for (int q = 0; q < 4; q++) {
                long grow = row0 + mrow + q;
                if (grow < M) {
                    float v = acc[r][c][q] + bb;
                    if (do_relu) v = fmaxf(v, 0.f);
                    if (out_bf16) ((bf16_t*)outp)[grow * 128 + col] = (bf16_t)v;
                    else          ((float*)outp)[grow * 128 + col] = v;
                    if (bn_sums) { atomicAdd(&bsum[col], v); atomicAdd(&bsq[col], v * v); }
                }
            }
        }
    }
    if (bn_sums) {
        __syncthreads();
        if (tid < 128) {
            atomicAdd(&bn_sums[tid], bsum[tid]);
            atomicAdd(&bn_sums[128 + tid], bsq[tid]);
        }
    }
}

// ---------------------------------------------------------------------------
// Fused edge encoder: e = (relu(ea @ W1 + b1)) @ W2 + b2, rows written in
// dst-sorted (CSR) order via rank[].
// ---------------------------------------------------------------------------
__global__ __launch_bounds__(256) void edge_mlp_kernel(
    const float* __restrict__ A, int M,
    const bf16_t* __restrict__ Ws1, const float* __restrict__ b1,
    const bf16_t* __restrict__ Ws2, const float* __restrict__ b2,
    const int* __restrict__ rank, bf16_t* __restrict__ outp)
{
    constexpr int S1 = 40, S2 = 136;
    __shared__ bf16_t Als[128 * S1];
    __shared__ bf16_t Hls[128 * S2];
    __shared__ float  bls1[128], bls2[128];

    const int  tid  = threadIdx.x;
    const long row0 = (long)blockIdx.x * 128;

    if (tid < 128) { bls1[tid] = b1[tid]; bls2[tid] = b2[tid]; }

    for (int i = tid; i < 128 * 8; i += 256) {
        int r = i / 8, c4 = (i % 8) * 4;
        long gr = row0 + r;
        float4 v = make_float4(0.f, 0.f, 0.f, 0.f);
        if (gr < M && c4 < 16) v = *(const float4*)(A + gr * 16 + c4);
        bf16_t* d = &Als[r * S1 + c4];
        d[0] = (bf16_t)v.x; d[1] = (bf16_t)v.y; d[2] = (bf16_t)v.z; d[3] = (bf16_t)v.w;
    }
    __syncthreads();

    const int wv = tid >> 6, lane = tid & 63;
    const int l16 = lane & 15, quad = lane >> 4;

    f32x4 acc[2][8];
#pragma unroll
    for (int r = 0; r < 2; r++)
#pragma unroll
        for (int c = 0; c < 8; c++) acc[r][c] = (f32x4){0.f, 0.f, 0.f, 0.f};

    {
        bf16x8 af0 = *(const bf16x8*)&Als[(wv * 32 + l16) * S1 + quad * 8];
        bf16x8 af1 = *(const bf16x8*)&Als[(wv * 32 + 16 + l16) * S1 + quad * 8];
#pragma unroll
        for (int c = 0; c < 8; c++) {
            bf16x8 bfr = *(const bf16x8*)&Ws1[((c * 64) + lane) * 8];
            acc[0][c] = MFMA16(af0, bfr, acc[0][c]);
            acc[1][c] = MFMA16(af1, bfr, acc[1][c]);
        }
    }
#pragma unroll
    for (int r = 0; r < 2; r++) {
        int mrow = wv * 32 + r * 16 + quad * 4;
#pragma unroll
        for (int c = 0; c < 8; c++) {
            int col = c * 16 + l16;
            float bb = bls1[col];
#pragma unroll
            for (int q = 0; q < 4; q++) {
                float v = fmaxf(acc[r][c][q] + bb, 0.f);
                Hls[(mrow + q) * S2 + col] = (bf16_t)v;
            }
        }
    }
    __syncthreads();

#pragma unroll
    for (int r = 0; r < 2; r++)
#pragma unroll
        for (int c = 0; c < 8; c++) acc[r][c] = (f32x4){0.f, 0.f, 0.f, 0.f};

#pragma unroll
    for (int kc = 0; kc < 4; ++kc) {
        bf16x8 af0 = *(const bf16x8*)&Hls[(wv * 32 + l16) * S2 + kc * 32 + quad * 8];
        bf16x8 af1 = *(const bf16x8*)&Hls[(wv * 32 + 16 + l16) * S2 + kc * 32 + quad * 8];
#pragma unroll
        for (int c = 0; c < 8; c++) {
            bf16x8 bfr = *(const bf16x8*)&Ws2[(((kc * 8 + c) * 64) + lane) * 8];
            acc[0][c] = MFMA16(af0, bfr, acc[0][c]);
            acc[1][c] = MFMA16(af1, bfr, acc[1][c]);
        }
    }
#pragma unroll
    for (int r = 0; r < 2; r++) {
        int mrow = wv * 32 + r * 16 + quad * 4;
#pragma unroll
        for (int q = 0; q < 4; q++) {
            long grow = row0 + mrow + q;
            if (grow < M) {
                long prow = rank[grow];
#pragma unroll
                for (int c = 0; c < 8; c++) {
                    int col = c * 16 + l16;
                    outp[prow * 128 + col] = (bf16_t)(acc[r][c][q] + bls2[col]);
                }
            }
        }
    }
}

// ---------------------------------------------------------------------------
// CSR gather aggregation: aggr[n] = h[n] + sum_{i in [rowptr[n],rowptr[n+1])}
//   relu(h[srcp[i]] + e[i]).  One wave per node, 2 channels per lane.
// ---------------------------------------------------------------------------
__global__ __launch_bounds__(256) void aggr_kernel(
    const float* __restrict__ h, const bf16_t* __restrict__ e,
    const int* __restrict__ rowptr, const int* __restrict__ srcp,
    float* __restrict__ aggr, int N)
{
    int wid = (int)(((long)blockIdx.x * 256 + threadIdx.x) >> 6);
    if (wid >= N) return;
    int lane = threadIdx.x & 63;
    const float2* hp = (const float2*)h;
    float2 acc = hp[(long)wid * 64 + lane];   // self term (eps=0)
    int beg = rowptr[wid], end = rowptr[wid + 1];
    int i = beg;
    for (; i + 1 < end; i += 2) {
        int s0 = srcp[i], s1 = srcp[i + 1];
        float2 h0 = hp[(long)s0 * 64 + lane];
        float2 h1 = hp[(long)s1 * 64 + lane];
        bf16x2 e0 = *(const bf16x2*)(e + (long)i * 128 + lane * 2);
        bf16x2 e1 = *(const bf16x2*)(e + ((long)i + 1) * 128 + lane * 2);
        acc.x += fmaxf(h0.x + (float)e0[0], 0.f);
        acc.y += fmaxf(h0.y + (float)e0[1], 0.f);
        acc.x += fmaxf(h1.x + (float)e1[0], 0.f);
        acc.y += fmaxf(h1.y + (float)e1[1], 0.f);
    }
    if (i < end) {
        int s0 = srcp[i];
        float2 h0 = hp[(long)s0 * 64 + lane];
        bf16x2 e0 = *(const bf16x2*)(e + (long)i * 128 + lane * 2);
        acc.x += fmaxf(h0.x + (float)e0[0], 0.f);
        acc.y += fmaxf(h0.y + (float)e0[1], 0.f);
    }
    ((float2*)aggr)[(long)wid * 64 + lane] = acc;
}

// ---------------------------------------------------------------------------
__global__ void bn_fin_kernel(const float* __restrict__ sums, const float* __restrict__ gamma,
                              const float* __restrict__ beta, float* __restrict__ scsh, int N)
{
    int c = threadIdx.x;
    float mean = sums[c] / (float)N;
    float var  = sums[128 + c] / (float)N - mean * mean;
    float inv  = rsqrtf(var + 1e-5f);
    float sc   = gamma[c] * inv;
    scsh[c]       = sc;
    scsh[128 + c] = beta[c] - mean * sc;
}

__global__ __launch_bounds__(256) void bn_apply_kernel(
    const float* z, const float* scsh, float* h, long total)
{
    long idx = (long)blockIdx.x * 256 + threadIdx.x;
    if (idx >= total) return;
    int c = (int)(idx & 127);
    h[idx] = fmaxf(z[idx] * scsh[c] + scsh[128 + c], 0.f);
}

// ---------------------------------------------------------------------------
__global__ __launch_bounds__(128) void pool_kernel(
    const float* __restrict__ h, const int* __restrict__ batch,
    float* __restrict__ gsum, float* __restrict__ cnt, int N)
{
    int c = threadIdx.x;
    int n0 = blockIdx.x * 256;
    int n1 = min(n0 + 256, N);
    float acc = 0.f;
    int cur = -1, rc = 0;
    for (int n = n0; n < n1; ++n) {
        int g = batch[n];
        if (g != cur) {
            if (cur >= 0) {
                atomicAdd(&gsum[(long)cur * 128 + c], acc);
                if (c == 0) atomicAdd(&cnt[cur], (float)rc);
            }
            cur = g; acc = 0.f; rc = 0;
        }
        acc += h[(long)n * 128 + c];
        rc++;
    }
    if (cur >= 0) {
        atomicAdd(&gsum[(long)cur * 128 + c], acc);
        if (c == 0) atomicAdd(&cnt[cur], (float)rc);
    }
}

__global__ __launch_bounds__(128) void head_kernel(
    const float* __restrict__ gsum, const float* __restrict__ cnt,
    const float* __restrict__ ext_in,
    const float* __restrict__ ew1, const float* __restrict__ eb1,
    const float* __restrict__ ew2, const float* __restrict__ eb2,
    const float* __restrict__ rw1, const float* __restrict__ rb1,
    const float* __restrict__ rw2, const float* __restrict__ rb2,
    float* __restrict__ out)
{
    int g = blockIdx.x, c = threadIdx.x;
    __shared__ float sx[8];
    __shared__ float h1[128];
    __shared__ float comb[256];
    __shared__ float red[128];

    if (c < 8) sx[c] = ext_in[g * 8 + c];
    __syncthreads();
    float a = eb1[c];
#pragma unroll
    for (int k = 0; k < 8; k++) a += sx[k] * ew1[k * 128 + c];
    h1[c] = fmaxf(a, 0.f);
    __syncthreads();
    float b = eb2[c];
    for (int k = 0; k < 128; k++) b += h1[k] * ew2[k * 128 + c];
    comb[c]       = gsum[(long)g * 128 + c] / fmaxf(cnt[g], 1.0f);
    comb[128 + c] = b;
    __syncthreads();
    float r = rb1[c];
    for (int k = 0; k < 256; k++) r += comb[k] * rw1[k * 128 + c];
    r = fmaxf(r, 0.f);
    red[c] = r * rw2[c];
    __syncthreads();
    if (c == 0) {
        float s = rb2[0];
        for (int k = 0; k < 128; k++) s += red[k];
        out[g] = s;
    }
}

// ---------------------------------------------------------------------------
extern "C" void kernel_launch(void* const* d_in, const int* in_sizes, int n_in,
                              void* d_out, int out_size, void* d_ws, size_t ws_size,
                              hipStream_t stream)
{
    const float* x         = (const float*)d_in[0];
    const float* edge_attr = (const float*)d_in[1];
    const float* externals = (const float*)d_in[2];
    const float* node_w    = (const float*)d_in[3];
    const float* node_b    = (const float*)d_in[4];
    const float* ee_w1     = (const float*)d_in[5];
    const float* ee_b1     = (const float*)d_in[6];
    const float* ee_w2     = (const float*)d_in[7];
    const float* ee_b2     = (const float*)d_in[8];
    const float* conv_w1   = (const float*)d_in[9];
    const float* conv_b1   = (const float*)d_in[10];
    const float* conv_w2   = (const float*)d_in[11];
    const float* conv_b2   = (const float*)d_in[12];
    const float* bn_gamma  = (const float*)d_in[13];
    const float* bn_beta   = (const float*)d_in[14];
    const float* ext_w1    = (const float*)d_in[15];
    const float* ext_b1    = (const float*)d_in[16];
    const float* ext_w2    = (const float*)d_in[17];
    const float* ext_b2    = (const float*)d_in[18];
    const float* reg_w1    = (const float*)d_in[19];
    const float* reg_b1    = (const float*)d_in[20];
    const float* reg_w2    = (const float*)d_in[21];
    const float* reg_b2    = (const float*)d_in[22];
    const int* edge_index  = (const int*)d_in[23];
    const int* batch       = (const int*)d_in[24];

    const int N = in_sizes[0] / 32;
    const int E = in_sizes[1] / 16;
    const int G = in_sizes[2] / 8;

    char* p = (char*)d_ws;
    auto alloc = [&](size_t bytes) -> void* {
        void* r = (void*)p;
        p += (bytes + 255) & ~(size_t)255;
        return r;
    };
    float*  h       = (float*)alloc((size_t)N * 128 * sizeof(float));
    float*  aggr    = (float*)alloc((size_t)N * 128 * sizeof(float));   // also z2
    bf16_t* tbuf    = (bf16_t*)alloc((size_t)N * 128 * sizeof(bf16_t)); // conv hidden
    bf16_t* ebuf    = (bf16_t*)alloc((size_t)E * 128 * sizeof(bf16_t)); // dst-sorted
    int*    deg     = (int*)alloc((size_t)N * 4);
    int*    rowptr  = (int*)alloc(((size_t)N + 1) * 4);
    int*    cursor  = (int*)alloc((size_t)N * 4);
    int*    srcp    = (int*)alloc((size_t)E * 4);
    int*    rank    = (int*)alloc((size_t)E * 4);
    bf16_t* node_wt = (bf16_t*)alloc(128 * 32 * 2);
    bf16_t* ee_w1t  = (bf16_t*)alloc(128 * 32 * 2);
    bf16_t* ee_w2t  = (bf16_t*)alloc(128 * 128 * 2);
    bf16_t* cw1t    = (bf16_t*)alloc(3 * 128 * 128 * 2);
    bf16_t* cw2t    = (bf16_t*)alloc(3 * 128 * 128 * 2);
    float*  bn_sums = (float*)alloc(256 * 4);
    float*  scsh    = (float*)alloc(256 * 4);
    float*  gsum    = (float*)alloc((size_t)G * 128 * 4);
    float*  cnt     = (float*)alloc((size_t)G * 4);

    // --- CSR build (by dst) ---
    hipMemsetAsync(deg, 0, (size_t)N * 4, stream);
    hist_kernel<<<(E + 255) / 256, 256, 0, stream>>>(edge_index, deg, E);
    scan_kernel<<<1, 1024, 0, stream>>>(deg, rowptr, cursor, N);
    scatter_kernel<<<(E + 255) / 256, 256, 0, stream>>>(edge_index, cursor, srcp, rank, E);

    // --- weight prep ---
    prep_w_kernel<<<16, 256, 0, stream>>>(node_w, node_wt, 32, 32);
    prep_w_kernel<<<16, 256, 0, stream>>>(ee_w1, ee_w1t, 16, 32);
    prep_w_kernel<<<64, 256, 0, stream>>>(ee_w2, ee_w2t, 128, 128);
    for (int l = 0; l < 3; l++) {
        prep_w_kernel<<<64, 256, 0, stream>>>(conv_w1 + l * 16384, cw1t + l * 16384, 128, 128);
        prep_w_kernel<<<64, 256, 0, stream>>>(conv_w2 + l * 16384, cw2t + l * 16384, 128, 128);
    }

    // --- node encoder: h = x @ node_w + node_b ---
    gemm_kernel<32><<<(N + 127) / 128, 256, 0, stream>>>(
        x, 1, N, 32, node_wt, node_b, 0, h, 0, nullptr);

    // --- edge encoder -> ebuf in CSR order ---
    edge_mlp_kernel<<<(E + 127) / 128, 256, 0, stream>>>(
        edge_attr, E, ee_w1t, ee_b1, ee_w2t, ee_b2, rank, ebuf);

    // --- GINE layers ---
    for (int l = 0; l < 3; l++) {
        aggr_kernel<<<(N + 3) / 4, 256, 0, stream>>>(h, ebuf, rowptr, srcp, aggr, N);
        hipMemsetAsync(bn_sums, 0, 256 * 4, stream);
        gemm_kernel<128><<<(N + 127) / 128, 256, 0, stream>>>(
            aggr, 1, N, 128, cw1t + l * 16384, conv_b1 + l * 128, 1, tbuf, 1, nullptr);
        gemm_kernel<128><<<(N + 127) / 128, 256, 0, stream>>>(
            tbuf, 0, N, 128, cw2t + l * 16384, conv_b2 + l * 128, 0, aggr, 0, bn_sums);
        bn_fin_kernel<<<1, 128, 0, stream>>>(bn_sums, bn_gamma + l * 128, bn_beta + l * 128, scsh, N);
        bn_apply_kernel<<<(int)(((long)N * 128 + 255) / 256), 256, 0, stream>>>(
            aggr, scsh, h, (long)N * 128);
    }

    // --- pooling + head ---
    hipMemsetAsync(gsum, 0, (size_t)G * 128 * 4, stream);
    hipMemsetAsync(cnt, 0, (size_t)G * 4, stream);
    pool_kernel<<<(N + 255) / 256, 128, 0, stream>>>(h, batch, gsum, cnt, N);
    head_kernel<<<G, 128, 0, stream>>>(gsum, cnt, externals,
                                       ext_w1, ext_b1, ext_w2, ext_b2,
                                       reg_w1, reg_b1, reg_w2, reg_b2,
                                       (float*)d_out);
}

// Round 3
// 1010.111 us; speedup vs baseline: 3.9383x; 1.1002x over previous
//
#include <hip/hip_runtime.h>

typedef __bf16 bf16_t;
typedef __bf16 bf16x8 __attribute__((ext_vector_type(8)));
typedef __bf16 bf16x4 __attribute__((ext_vector_type(4)));
typedef __bf16 bf16x2 __attribute__((ext_vector_type(2)));
typedef float  f32x4  __attribute__((ext_vector_type(4)));

#define MFMA16(a, b, c) __builtin_amdgcn_mfma_f32_16x16x32_bf16((a), (b), (c), 0, 0, 0)

// ---------------------------------------------------------------------------
// Weight prep: W [Kact,128] f32 row-major -> bf16 MFMA-B-fragment-sequential:
// idx = ((kc*8 + ctile)*64 + lane)*8 + j ; n = ctile*16+(lane&15),
// k = kc*32+(lane>>4)*8+j, zero-pad k>=Kact.
// ---------------------------------------------------------------------------
__global__ void prep_w_kernel(const float* __restrict__ W, bf16_t* __restrict__ Ws,
                              int Kact, int KP) {
    int idx = blockIdx.x * 256 + threadIdx.x;
    if (idx >= 128 * KP) return;
    int j    = idx & 7;
    int lane = (idx >> 3) & 63;
    int ct   = (idx >> 9) & 7;
    int kc   = idx >> 12;
    int n = ct * 16 + (lane & 15);
    int k = kc * 32 + (lane >> 4) * 8 + j;
    Ws[idx] = (bf16_t)((k < Kact) ? W[k * 128 + n] : 0.0f);
}

// ---------------------------------------------------------------------------
// CSR build: histogram of dst -> 3-phase device-wide scan -> scatter perm.
// ---------------------------------------------------------------------------
__global__ __launch_bounds__(256) void hist_kernel(const int* __restrict__ ei,
                                                   int* __restrict__ deg, int E) {
    int t = blockIdx.x * 256 + threadIdx.x;
    if (t < E) atomicAdd(&deg[ei[(long)E + t]], 1);
}

// Phase A: per-block (1024 elems) exclusive scan -> partials, block sum -> bsums
__global__ __launch_bounds__(256) void scanA_kernel(const int* __restrict__ deg,
                                                    int* __restrict__ partials,
                                                    int* __restrict__ bsums, int N) {
    __shared__ int s[256];
    int b = blockIdx.x, t = threadIdx.x;
    int base = b * 1024 + t * 4;
    int v0 = (base + 0 < N) ? deg[base + 0] : 0;
    int v1 = (base + 1 < N) ? deg[base + 1] : 0;
    int v2 = (base + 2 < N) ? deg[base + 2] : 0;
    int v3 = (base + 3 < N) ? deg[base + 3] : 0;
    int local = v0 + v1 + v2 + v3;
    s[t] = local;
    __syncthreads();
    for (int off = 1; off < 256; off <<= 1) {
        int v = (t >= off) ? s[t - off] : 0;
        __syncthreads();
        s[t] += v;
        __syncthreads();
    }
    int excl = s[t] - local;
    if (base + 0 < N) partials[base + 0] = excl;
    if (base + 1 < N) partials[base + 1] = excl + v0;
    if (base + 2 < N) partials[base + 2] = excl + v0 + v1;
    if (base + 3 < N) partials[base + 3] = excl + v0 + v1 + v2;
    if (t == 255) bsums[b] = s[255];
}

// Phase B: single block scans NB block sums -> boff (exclusive), rowptr[N]=total
__global__ __launch_bounds__(256) void scanB_kernel(const int* __restrict__ bsums,
                                                    int* __restrict__ boff,
                                                    int* __restrict__ rowptr,
                                                    int NB, int N) {
    __shared__ int s[256];
    int t = threadIdx.x;
    int local = (t < NB) ? bsums[t] : 0;
    s[t] = local;
    __syncthreads();
    for (int off = 1; off < 256; off <<= 1) {
        int v = (t >= off) ? s[t - off] : 0;
        __syncthreads();
        s[t] += v;
        __syncthreads();
    }
    if (t < NB) boff[t] = s[t] - local;
    if (t == NB - 1) rowptr[N] = s[t];
}

// Phase C: rowptr[i] = cursor[i] = partials[i] + boff[i/1024]
__global__ __launch_bounds__(256) void scanC_kernel(const int* __restrict__ partials,
                                                    const int* __restrict__ boff,
                                                    int* __restrict__ rowptr,
                                                    int* __restrict__ cursor, int N) {
    int i = blockIdx.x * 256 + threadIdx.x;
    if (i >= N) return;
    int v = partials[i] + boff[i >> 10];
    rowptr[i] = v;
    cursor[i] = v;
}

__global__ __launch_bounds__(256) void scatter_kernel(const int* __restrict__ ei,
                                                      int* __restrict__ cursor,
                                                      int* __restrict__ srcp,
                                                      int* __restrict__ rank, int E) {
    int t = blockIdx.x * 256 + threadIdx.x;
    if (t >= E) return;
    int d = ei[(long)E + t];
    int pos = atomicAdd(&cursor[d], 1);
    srcp[pos] = ei[t];
    rank[t] = pos;
}

// ---------------------------------------------------------------------------
// Generic single-GEMM: out[M,128] = act(A[M,Kact] @ W + bias)
// A f32 (cast->bf16 while staging) or bf16 (stride KP). Optional BN sums.
// 128 rows/block, 256 threads, 16x16x32 bf16 MFMA, B-frags from global.
// ---------------------------------------------------------------------------
template <int KP>
__global__ __launch_bounds__(256) void gemm_kernel(
    const void* Ap, int a_is_f32, int M, int Kact,
    const bf16_t* __restrict__ Ws, const float* __restrict__ bias,
    int do_relu, void* outp, int out_bf16, float* bn_sums)
{
    constexpr int S1 = KP + 8;
    __shared__ bf16_t Als[128 * S1];
    __shared__ float  bls[128];
    __shared__ float  bsum[128];
    __shared__ float  bsq[128];

    const int  tid  = threadIdx.x;
    const long row0 = (long)blockIdx.x * 128;

    if (tid < 128) { bls[tid] = bias[tid]; bsum[tid] = 0.f; bsq[tid] = 0.f; }

    if (a_is_f32) {
        const float* A = (const float*)Ap;
        constexpr int U = KP / 4;
        for (int i = tid; i < 128 * U; i += 256) {
            int r = i / U, c4 = (i % U) * 4;
            long gr = row0 + r;
            float4 v = make_float4(0.f, 0.f, 0.f, 0.f);
            if (gr < M && c4 < Kact) v = *(const float4*)(A + gr * Kact + c4);
            bf16_t* d = &Als[r * S1 + c4];
            d[0] = (bf16_t)v.x; d[1] = (bf16_t)v.y; d[2] = (bf16_t)v.z; d[3] = (bf16_t)v.w;
        }
    } else {
        const bf16_t* A = (const bf16_t*)Ap;
        constexpr int U = KP / 8;
        for (int i = tid; i < 128 * U; i += 256) {
            int r = i / U, c8 = (i % U) * 8;
            long gr = row0 + r;
            uint4 v = make_uint4(0u, 0u, 0u, 0u);
            if (gr < M) v = *(const uint4*)(A + gr * KP + c8);
            *(uint4*)&Als[r * S1 + c8] = v;
        }
    }
    __syncthreads();

    const int wv = tid >> 6, lane = tid & 63;
    const int l16 = lane & 15, quad = lane >> 4;

    f32x4 acc[2][8];
#pragma unroll
    for (int r = 0; r < 2; r++)
#pragma unroll
        for (int c = 0; c < 8; c++) acc[r][c] = (f32x4){0.f, 0.f, 0.f, 0.f};

#pragma unroll
    for (int kc = 0; kc < KP / 32; ++kc) {
        bf16x8 af0 = *(const bf16x8*)&Als[(wv * 32 + l16) * S1 + kc * 32 + quad * 8];
        bf16x8 af1 = *(const bf16x8*)&Als[(wv * 32 + 16 + l16) * S1 + kc * 32 + quad * 8];
#pragma unroll
        for (int c = 0; c < 8; c++) {
            bf16x8 bfr = *(const bf16x8*)&Ws[(((kc * 8 + c) * 64) + lane) * 8];
            acc[0][c] = MFMA16(af0, bfr, acc[0][c]);
            acc[1][c] = MFMA16(af1, bfr, acc[1][c]);
        }
    }

#pragma unroll
    for (int r = 0; r < 2; r++) {
        int mrow = wv * 32 + r * 16 + quad * 4;
#pragma unroll
        for (int c = 0; c < 8; c++) {
            int col = c * 16 + l16;
            float bb = bls[col];
#pragma unroll
            for (int q = 0; q < 4; q++) {
                long grow = row0 + mrow + q;
                if (grow < M) {
                    float v = acc[r][c][q] + bb;
                    if (do_relu) v = fmaxf(v, 0.f);
                    if (out_bf16) ((bf16_t*)outp)[grow * 128 + col] = (bf16_t)v;
                    else          ((float*)outp)[grow * 128 + col] = v;
                    if (bn_sums) { atomicAdd(&bsum[col], v); atomicAdd(&bsq[col], v * v); }
                }
            }
        }
    }
    if (bn_sums) {
        __syncthreads();
        if (tid < 128) {
            atomicAdd(&bn_sums[tid], bsum[tid]);
            atomicAdd(&bn_sums[128 + tid], bsq[tid]);
        }
    }
}

// ---------------------------------------------------------------------------
// Fused edge encoder: e = (relu(ea @ W1 + b1)) @ W2 + b2, rows written in
// dst-sorted (CSR) order via rank[].
// ---------------------------------------------------------------------------
__global__ __launch_bounds__(256) void edge_mlp_kernel(
    const float* __restrict__ A, int M,
    const bf16_t* __restrict__ Ws1, const float* __restrict__ b1,
    const bf16_t* __restrict__ Ws2, const float* __restrict__ b2,
    const int* __restrict__ rank, bf16_t* __restrict__ outp)
{
    constexpr int S1 = 40, S2 = 136;
    __shared__ bf16_t Als[128 * S1];
    __shared__ bf16_t Hls[128 * S2];
    __shared__ float  bls1[128], bls2[128];

    const int  tid  = threadIdx.x;
    const long row0 = (long)blockIdx.x * 128;

    if (tid < 128) { bls1[tid] = b1[tid]; bls2[tid] = b2[tid]; }

    for (int i = tid; i < 128 * 8; i += 256) {
        int r = i / 8, c4 = (i % 8) * 4;
        long gr = row0 + r;
        float4 v = make_float4(0.f, 0.f, 0.f, 0.f);
        if (gr < M && c4 < 16) v = *(const float4*)(A + gr * 16 + c4);
        bf16_t* d = &Als[r * S1 + c4];
        d[0] = (bf16_t)v.x; d[1] = (bf16_t)v.y; d[2] = (bf16_t)v.z; d[3] = (bf16_t)v.w;
    }
    __syncthreads();

    const int wv = tid >> 6, lane = tid & 63;
    const int l16 = lane & 15, quad = lane >> 4;

    f32x4 acc[2][8];
#pragma unroll
    for (int r = 0; r < 2; r++)
#pragma unroll
        for (int c = 0; c < 8; c++) acc[r][c] = (f32x4){0.f, 0.f, 0.f, 0.f};

    {
        bf16x8 af0 = *(const bf16x8*)&Als[(wv * 32 + l16) * S1 + quad * 8];
        bf16x8 af1 = *(const bf16x8*)&Als[(wv * 32 + 16 + l16) * S1 + quad * 8];
#pragma unroll
        for (int c = 0; c < 8; c++) {
            bf16x8 bfr = *(const bf16x8*)&Ws1[((c * 64) + lane) * 8];
            acc[0][c] = MFMA16(af0, bfr, acc[0][c]);
            acc[1][c] = MFMA16(af1, bfr, acc[1][c]);
        }
    }
#pragma unroll
    for (int r = 0; r < 2; r++) {
        int mrow = wv * 32 + r * 16 + quad * 4;
#pragma unroll
        for (int c = 0; c < 8; c++) {
            int col = c * 16 + l16;
            float bb = bls1[col];
#pragma unroll
            for (int q = 0; q < 4; q++) {
                float v = fmaxf(acc[r][c][q] + bb, 0.f);
                Hls[(mrow + q) * S2 + col] = (bf16_t)v;
            }
        }
    }
    __syncthreads();

#pragma unroll
    for (int r = 0; r < 2; r++)
#pragma unroll
        for (int c = 0; c < 8; c++) acc[r][c] = (f32x4){0.f, 0.f, 0.f, 0.f};

#pragma unroll
    for (int kc = 0; kc < 4; ++kc) {
        bf16x8 af0 = *(const bf16x8*)&Hls[(wv * 32 + l16) * S2 + kc * 32 + quad * 8];
        bf16x8 af1 = *(const bf16x8*)&Hls[(wv * 32 + 16 + l16) * S2 + kc * 32 + quad * 8];
#pragma unroll
        for (int c = 0; c < 8; c++) {
            bf16x8 bfr = *(const bf16x8*)&Ws2[(((kc * 8 + c) * 64) + lane) * 8];
            acc[0][c] = MFMA16(af0, bfr, acc[0][c]);
            acc[1][c] = MFMA16(af1, bfr, acc[1][c]);
        }
    }
#pragma unroll
    for (int r = 0; r < 2; r++) {
        int mrow = wv * 32 + r * 16 + quad * 4;
#pragma unroll
        for (int q = 0; q < 4; q++) {
            long grow = row0 + mrow + q;
            if (grow < M) {
                long prow = rank[grow];
#pragma unroll
                for (int c = 0; c < 8; c++) {
                    int col = c * 16 + l16;
                    outp[prow * 128 + col] = (bf16_t)(acc[r][c][q] + bls2[col]);
                }
            }
        }
    }
}

// ---------------------------------------------------------------------------
// CSR gather aggregation: aggr[n] = h[n] + sum_{i in [rowptr[n],rowptr[n+1])}
//   relu(h[srcp[i]] + e[i]).  One wave per node, 2 channels per lane.
// ---------------------------------------------------------------------------
__global__ __launch_bounds__(256) void aggr_kernel(
    const float* __restrict__ h, const bf16_t* __restrict__ e,
    const int* __restrict__ rowptr, const int* __restrict__ srcp,
    float* __restrict__ aggr, int N)
{
    int wid = (int)(((long)blockIdx.x * 256 + threadIdx.x) >> 6);
    if (wid >= N) return;
    int lane = threadIdx.x & 63;
    const float2* hp = (const float2*)h;
    float2 acc = hp[(long)wid * 64 + lane];   // self term (eps=0)
    int beg = rowptr[wid], end = rowptr[wid + 1];
    int i = beg;
    for (; i + 1 < end; i += 2) {
        int s0 = srcp[i], s1 = srcp[i + 1];
        float2 h0 = hp[(long)s0 * 64 + lane];
        float2 h1 = hp[(long)s1 * 64 + lane];
        bf16x2 e0 = *(const bf16x2*)(e + (long)i * 128 + lane * 2);
        bf16x2 e1 = *(const bf16x2*)(e + ((long)i + 1) * 128 + lane * 2);
        acc.x += fmaxf(h0.x + (float)e0[0], 0.f);
        acc.y += fmaxf(h0.y + (float)e0[1], 0.f);
        acc.x += fmaxf(h1.x + (float)e1[0], 0.f);
        acc.y += fmaxf(h1.y + (float)e1[1], 0.f);
    }
    if (i < end) {
        int s0 = srcp[i];
        float2 h0 = hp[(long)s0 * 64 + lane];
        bf16x2 e0 = *(const bf16x2*)(e + (long)i * 128 + lane * 2);
        acc.x += fmaxf(h0.x + (float)e0[0], 0.f);
        acc.y += fmaxf(h0.y + (float)e0[1], 0.f);
    }
    ((float2*)aggr)[(long)wid * 64 + lane] = acc;
}

// ---------------------------------------------------------------------------
__global__ void bn_fin_kernel(const float* __restrict__ sums, const float* __restrict__ gamma,
                              const float* __restrict__ beta, float* __restrict__ scsh, int N)
{
    int c = threadIdx.x;
    float mean = sums[c] / (float)N;
    float var  = sums[128 + c] / (float)N - mean * mean;
    float inv  = rsqrtf(var + 1e-5f);
    float sc   = gamma[c] * inv;
    scsh[c]       = sc;
    scsh[128 + c] = beta[c] - mean * sc;
}

__global__ __launch_bounds__(256) void bn_apply_kernel(
    const float* z, const float* scsh, float* h, long total)
{
    long idx = (long)blockIdx.x * 256 + threadIdx.x;
    if (idx >= total) return;
    int c = (int)(idx & 127);
    h[idx] = fmaxf(z[idx] * scsh[c] + scsh[128 + c], 0.f);
}

// ---------------------------------------------------------------------------
__global__ __launch_bounds__(128) void pool_kernel(
    const float* __restrict__ h, const int* __restrict__ batch,
    float* __restrict__ gsum, float* __restrict__ cnt, int N)
{
    int c = threadIdx.x;
    int n0 = blockIdx.x * 256;
    int n1 = min(n0 + 256, N);
    float acc = 0.f;
    int cur = -1, rc = 0;
    for (int n = n0; n < n1; ++n) {
        int g = batch[n];
        if (g != cur) {
            if (cur >= 0) {
                atomicAdd(&gsum[(long)cur * 128 + c], acc);
                if (c == 0) atomicAdd(&cnt[cur], (float)rc);
            }
            cur = g; acc = 0.f; rc = 0;
        }
        acc += h[(long)n * 128 + c];
        rc++;
    }
    if (cur >= 0) {
        atomicAdd(&gsum[(long)cur * 128 + c], acc);
        if (c == 0) atomicAdd(&cnt[cur], (float)rc);
    }
}

__global__ __launch_bounds__(128) void head_kernel(
    const float* __restrict__ gsum, const float* __restrict__ cnt,
    const float* __restrict__ ext_in,
    const float* __restrict__ ew1, const float* __restrict__ eb1,
    const float* __restrict__ ew2, const float* __restrict__ eb2,
    const float* __restrict__ rw1, const float* __restrict__ rb1,
    const float* __restrict__ rw2, const float* __restrict__ rb2,
    float* __restrict__ out)
{
    int g = blockIdx.x, c = threadIdx.x;
    __shared__ float sx[8];
    __shared__ float h1[128];
    __shared__ float comb[256];
    __shared__ float red[128];

    if (c < 8) sx[c] = ext_in[g * 8 + c];
    __syncthreads();
    float a = eb1[c];
#pragma unroll
    for (int k = 0; k < 8; k++) a += sx[k] * ew1[k * 128 + c];
    h1[c] = fmaxf(a, 0.f);
    __syncthreads();
    float b = eb2[c];
    for (int k = 0; k < 128; k++) b += h1[k] * ew2[k * 128 + c];
    comb[c]       = gsum[(long)g * 128 + c] / fmaxf(cnt[g], 1.0f);
    comb[128 + c] = b;
    __syncthreads();
    float r = rb1[c];
    for (int k = 0; k < 256; k++) r += comb[k] * rw1[k * 128 + c];
    r = fmaxf(r, 0.f);
    red[c] = r * rw2[c];
    __syncthreads();
    if (c == 0) {
        float s = rb2[0];
        for (int k = 0; k < 128; k++) s += red[k];
        out[g] = s;
    }
}

// ---------------------------------------------------------------------------
extern "C" void kernel_launch(void* const* d_in, const int* in_sizes, int n_in,
                              void* d_out, int out_size, void* d_ws, size_t ws_size,
                              hipStream_t stream)
{
    const float* x         = (const float*)d_in[0];
    const float* edge_attr = (const float*)d_in[1];
    const float* externals = (const float*)d_in[2];
    const float* node_w    = (const float*)d_in[3];
    const float* node_b    = (const float*)d_in[4];
    const float* ee_w1     = (const float*)d_in[5];
    const float* ee_b1     = (const float*)d_in[6];
    const float* ee_w2     = (const float*)d_in[7];
    const float* ee_b2     = (const float*)d_in[8];
    const float* conv_w1   = (const float*)d_in[9];
    const float* conv_b1   = (const float*)d_in[10];
    const float* conv_w2   = (const float*)d_in[11];
    const float* conv_b2   = (const float*)d_in[12];
    const float* bn_gamma  = (const float*)d_in[13];
    const float* bn_beta   = (const float*)d_in[14];
    const float* ext_w1    = (const float*)d_in[15];
    const float* ext_b1    = (const float*)d_in[16];
    const float* ext_w2    = (const float*)d_in[17];
    const float* ext_b2    = (const float*)d_in[18];
    const float* reg_w1    = (const float*)d_in[19];
    const float* reg_b1    = (const float*)d_in[20];
    const float* reg_w2    = (const float*)d_in[21];
    const float* reg_b2    = (const float*)d_in[22];
    const int* edge_index  = (const int*)d_in[23];
    const int* batch       = (const int*)d_in[24];

    const int N = in_sizes[0] / 32;
    const int E = in_sizes[1] / 16;
    const int G = in_sizes[2] / 8;
    const int NB = (N + 1023) / 1024;

    char* p = (char*)d_ws;
    auto alloc = [&](size_t bytes) -> void* {
        void* r = (void*)p;
        p += (bytes + 255) & ~(size_t)255;
        return r;
    };
    float*  h       = (float*)alloc((size_t)N * 128 * sizeof(float));
    float*  aggr    = (float*)alloc((size_t)N * 128 * sizeof(float));   // also z2
    bf16_t* tbuf    = (bf16_t*)alloc((size_t)N * 128 * sizeof(bf16_t)); // conv hidden
    bf16_t* ebuf    = (bf16_t*)alloc((size_t)E * 128 * sizeof(bf16_t)); // dst-sorted
    int*    deg     = (int*)alloc((size_t)N * 4);
    int*    rowptr  = (int*)alloc(((size_t)N + 1) * 4);
    int*    cursor  = (int*)alloc((size_t)N * 4);
    int*    partials= (int*)alloc((size_t)N * 4);
    int*    bsums   = (int*)alloc((size_t)NB * 4);
    int*    boff    = (int*)alloc((size_t)NB * 4);
    int*    srcp    = (int*)alloc((size_t)E * 4);
    int*    rank    = (int*)alloc((size_t)E * 4);
    bf16_t* node_wt = (bf16_t*)alloc(128 * 32 * 2);
    bf16_t* ee_w1t  = (bf16_t*)alloc(128 * 32 * 2);
    bf16_t* ee_w2t  = (bf16_t*)alloc(128 * 128 * 2);
    bf16_t* cw1t    = (bf16_t*)alloc(3 * 128 * 128 * 2);
    bf16_t* cw2t    = (bf16_t*)alloc(3 * 128 * 128 * 2);
    float*  bn_sums = (float*)alloc(256 * 4);
    float*  scsh    = (float*)alloc(256 * 4);
    float*  gsum    = (float*)alloc((size_t)G * 128 * 4);
    float*  cnt     = (float*)alloc((size_t)G * 4);

    // --- CSR build (by dst), 3-phase parallel scan ---
    hipMemsetAsync(deg, 0, (size_t)N * 4, stream);
    hist_kernel<<<(E + 255) / 256, 256, 0, stream>>>(edge_index, deg, E);
    scanA_kernel<<<NB, 256, 0, stream>>>(deg, partials, bsums, N);
    scanB_kernel<<<1, 256, 0, stream>>>(bsums, boff, rowptr, NB, N);
    scanC_kernel<<<(N + 255) / 256, 256, 0, stream>>>(partials, boff, rowptr, cursor, N);
    scatter_kernel<<<(E + 255) / 256, 256, 0, stream>>>(edge_index, cursor, srcp, rank, E);

    // --- weight prep ---
    prep_w_kernel<<<16, 256, 0, stream>>>(node_w, node_wt, 32, 32);
    prep_w_kernel<<<16, 256, 0, stream>>>(ee_w1, ee_w1t, 16, 32);
    prep_w_kernel<<<64, 256, 0, stream>>>(ee_w2, ee_w2t, 128, 128);
    for (int l = 0; l < 3; l++) {
        prep_w_kernel<<<64, 256, 0, stream>>>(conv_w1 + l * 16384, cw1t + l * 16384, 128, 128);
        prep_w_kernel<<<64, 256, 0, stream>>>(conv_w2 + l * 16384, cw2t + l * 16384, 128, 128);
    }

    // --- node encoder: h = x @ node_w + node_b ---
    gemm_kernel<32><<<(N + 127) / 128, 256, 0, stream>>>(
        x, 1, N, 32, node_wt, node_b, 0, h, 0, nullptr);

    // --- edge encoder -> ebuf in CSR order ---
    edge_mlp_kernel<<<(E + 127) / 128, 256, 0, stream>>>(
        edge_attr, E, ee_w1t, ee_b1, ee_w2t, ee_b2, rank, ebuf);

    // --- GINE layers ---
    for (int l = 0; l < 3; l++) {
        aggr_kernel<<<(N + 3) / 4, 256, 0, stream>>>(h, ebuf, rowptr, srcp, aggr, N);
        hipMemsetAsync(bn_sums, 0, 256 * 4, stream);
        gemm_kernel<128><<<(N + 127) / 128, 256, 0, stream>>>(
            aggr, 1, N, 128, cw1t + l * 16384, conv_b1 + l * 128, 1, tbuf, 1, nullptr);
        gemm_kernel<128><<<(N + 127) / 128, 256, 0, stream>>>(
            tbuf, 0, N, 128, cw2t + l * 16384, conv_b2 + l * 128, 0, aggr, 0, bn_sums);
        bn_fin_kernel<<<1, 128, 0, stream>>>(bn_sums, bn_gamma + l * 128, bn_beta + l * 128, scsh, N);
        bn_apply_kernel<<<(int)(((long)N * 128 + 255) / 256), 256, 0, stream>>>(
            aggr, scsh, h, (long)N * 128);
    }

    // --- pooling + head ---
    hipMemsetAsync(gsum, 0, (size_t)G * 128 * 4, stream);
    hipMemsetAsync(cnt, 0, (size_t)G * 4, stream);
    pool_kernel<<<(N + 255) / 256, 128, 0, stream>>>(h, batch, gsum, cnt, N);
    head_kernel<<<G, 128, 0, stream>>>(gsum, cnt, externals,
                                       ext_w1, ext_b1, ext_w2, ext_b2,
                                       reg_w1, reg_b1, reg_w2, reg_b2,
                                       (float*)d_out);
}

// Round 4
// 1000.437 us; speedup vs baseline: 3.9763x; 1.0097x over previous
//
#include <hip/hip_runtime.h>

typedef __bf16 bf16_t;
typedef __bf16 bf16x8 __attribute__((ext_vector_type(8)));
typedef __bf16 bf16x4 __attribute__((ext_vector_type(4)));
typedef __bf16 bf16x2 __attribute__((ext_vector_type(2)));
typedef float  f32x4  __attribute__((ext_vector_type(4)));

#define MFMA16(a, b, c) __builtin_amdgcn_mfma_f32_16x16x32_bf16((a), (b), (c), 0, 0, 0)

// ---------------------------------------------------------------------------
// Weight prep: W [Kact,128] f32 row-major -> bf16 MFMA-B-fragment-sequential:
// idx = ((kc*8 + ctile)*64 + lane)*8 + j ; n = ctile*16+(lane&15),
// k = kc*32+(lane>>4)*8+j, zero-pad k>=Kact.
// ---------------------------------------------------------------------------
__global__ void prep_w_kernel(const float* __restrict__ W, bf16_t* __restrict__ Ws,
                              int Kact, int KP) {
    int idx = blockIdx.x * 256 + threadIdx.x;
    if (idx >= 128 * KP) return;
    int j    = idx & 7;
    int lane = (idx >> 3) & 63;
    int ct   = (idx >> 9) & 7;
    int kc   = idx >> 12;
    int n = ct * 16 + (lane & 15);
    int k = kc * 32 + (lane >> 4) * 8 + j;
    Ws[idx] = (bf16_t)((k < Kact) ? W[k * 128 + n] : 0.0f);
}

// ---------------------------------------------------------------------------
// CSR build: histogram of dst -> 3-phase device-wide scan -> scatter perm.
// ---------------------------------------------------------------------------
__global__ __launch_bounds__(256) void hist_kernel(const int* __restrict__ ei,
                                                   int* __restrict__ deg, int E) {
    int t = blockIdx.x * 256 + threadIdx.x;
    if (t < E) atomicAdd(&deg[ei[(long)E + t]], 1);
}

__global__ __launch_bounds__(256) void scanA_kernel(const int* __restrict__ deg,
                                                    int* __restrict__ partials,
                                                    int* __restrict__ bsums, int N) {
    __shared__ int s[256];
    int b = blockIdx.x, t = threadIdx.x;
    int base = b * 1024 + t * 4;
    int v0 = (base + 0 < N) ? deg[base + 0] : 0;
    int v1 = (base + 1 < N) ? deg[base + 1] : 0;
    int v2 = (base + 2 < N) ? deg[base + 2] : 0;
    int v3 = (base + 3 < N) ? deg[base + 3] : 0;
    int local = v0 + v1 + v2 + v3;
    s[t] = local;
    __syncthreads();
    for (int off = 1; off < 256; off <<= 1) {
        int v = (t >= off) ? s[t - off] : 0;
        __syncthreads();
        s[t] += v;
        __syncthreads();
    }
    int excl = s[t] - local;
    if (base + 0 < N) partials[base + 0] = excl;
    if (base + 1 < N) partials[base + 1] = excl + v0;
    if (base + 2 < N) partials[base + 2] = excl + v0 + v1;
    if (base + 3 < N) partials[base + 3] = excl + v0 + v1 + v2;
    if (t == 255) bsums[b] = s[255];
}

__global__ __launch_bounds__(256) void scanB_kernel(const int* __restrict__ bsums,
                                                    int* __restrict__ boff,
                                                    int* __restrict__ rowptr,
                                                    int NB, int N) {
    __shared__ int s[256];
    int t = threadIdx.x;
    int local = (t < NB) ? bsums[t] : 0;
    s[t] = local;
    __syncthreads();
    for (int off = 1; off < 256; off <<= 1) {
        int v = (t >= off) ? s[t - off] : 0;
        __syncthreads();
        s[t] += v;
        __syncthreads();
    }
    if (t < NB) boff[t] = s[t] - local;
    if (t == NB - 1) rowptr[N] = s[t];
}

__global__ __launch_bounds__(256) void scanC_kernel(const int* __restrict__ partials,
                                                    const int* __restrict__ boff,
                                                    int* __restrict__ rowptr,
                                                    int* __restrict__ cursor, int N) {
    int i = blockIdx.x * 256 + threadIdx.x;
    if (i >= N) return;
    int v = partials[i] + boff[i >> 10];
    rowptr[i] = v;
    cursor[i] = v;
}

__global__ __launch_bounds__(256) void scatter_kernel(const int* __restrict__ ei,
                                                      int* __restrict__ cursor,
                                                      int* __restrict__ srcp,
                                                      int* __restrict__ rank, int E) {
    int t = blockIdx.x * 256 + threadIdx.x;
    if (t >= E) return;
    int d = ei[(long)E + t];
    int pos = atomicAdd(&cursor[d], 1);
    srcp[pos] = ei[t];
    rank[t] = pos;
}

// ---------------------------------------------------------------------------
// Node encoder GEMM: out[M,128] = A[M,32(pad)] @ W + bias, f32 in/out.
// ---------------------------------------------------------------------------
__global__ __launch_bounds__(256) void gemm32_kernel(
    const float* __restrict__ A, int M, int Kact,
    const bf16_t* __restrict__ Ws, const float* __restrict__ bias,
    float* __restrict__ outp)
{
    constexpr int S1 = 40;
    __shared__ bf16_t Als[128 * S1];
    __shared__ float  bls[128];

    const int  tid  = threadIdx.x;
    const long row0 = (long)blockIdx.x * 128;

    if (tid < 128) bls[tid] = bias[tid];

    for (int i = tid; i < 128 * 8; i += 256) {
        int r = i / 8, c4 = (i % 8) * 4;
        long gr = row0 + r;
        float4 v = make_float4(0.f, 0.f, 0.f, 0.f);
        if (gr < M && c4 < Kact) v = *(const float4*)(A + gr * Kact + c4);
        bf16_t* d = &Als[r * S1 + c4];
        d[0] = (bf16_t)v.x; d[1] = (bf16_t)v.y; d[2] = (bf16_t)v.z; d[3] = (bf16_t)v.w;
    }
    __syncthreads();

    const int wv = tid >> 6, lane = tid & 63;
    const int l16 = lane & 15, quad = lane >> 4;

    f32x4 acc[2][8];
#pragma unroll
    for (int r = 0; r < 2; r++)
#pragma unroll
        for (int c = 0; c < 8; c++) acc[r][c] = (f32x4){0.f, 0.f, 0.f, 0.f};

    {
        bf16x8 af0 = *(const bf16x8*)&Als[(wv * 32 + l16) * S1 + quad * 8];
        bf16x8 af1 = *(const bf16x8*)&Als[(wv * 32 + 16 + l16) * S1 + quad * 8];
#pragma unroll
        for (int c = 0; c < 8; c++) {
            bf16x8 bfr = *(const bf16x8*)&Ws[((c * 64) + lane) * 8];
            acc[0][c] = MFMA16(af0, bfr, acc[0][c]);
            acc[1][c] = MFMA16(af1, bfr, acc[1][c]);
        }
    }

#pragma unroll
    for (int r = 0; r < 2; r++) {
        int mrow = wv * 32 + r * 16 + quad * 4;
#pragma unroll
        for (int c = 0; c < 8; c++) {
            int col = c * 16 + l16;
            float bb = bls[col];
#pragma unroll
            for (int q = 0; q < 4; q++) {
                long grow = row0 + mrow + q;
                if (grow < M) outp[grow * 128 + col] = acc[r][c][q] + bb;
            }
        }
    }
}

// ---------------------------------------------------------------------------
// Fused edge encoder: e = (relu(ea @ W1 + b1)) @ W2 + b2, rows written in
// dst-sorted (CSR) order via rank[]. Single union LDS tile (A -> H -> Z),
// coalesced 256B-row output.
// ---------------------------------------------------------------------------
__global__ __launch_bounds__(256) void edge_mlp_kernel(
    const float* __restrict__ A, int M,
    const bf16_t* __restrict__ Ws1, const float* __restrict__ b1,
    const bf16_t* __restrict__ Ws2, const float* __restrict__ b2,
    const int* __restrict__ rank, bf16_t* __restrict__ outp)
{
    constexpr int S = 136;
    __shared__ bf16_t T[128 * S];      // 34.8 KB union: A(32 cols) / H / Z
    __shared__ float  bls1[128], bls2[128];
    __shared__ int    ranks[128];

    const int  tid  = threadIdx.x;
    const long row0 = (long)blockIdx.x * 128;

    if (tid < 128) {
        bls1[tid] = b1[tid];
        bls2[tid] = b2[tid];
        ranks[tid] = (row0 + tid < M) ? rank[row0 + tid] : 0;
    }

    // stage A: 128 rows x 16 f32 (pad cols 16..31 with zeros)
    for (int i = tid; i < 128 * 8; i += 256) {
        int r = i / 8, c4 = (i % 8) * 4;
        long gr = row0 + r;
        float4 v = make_float4(0.f, 0.f, 0.f, 0.f);
        if (gr < M && c4 < 16) v = *(const float4*)(A + gr * 16 + c4);
        bf16_t* d = &T[r * S + c4];
        d[0] = (bf16_t)v.x; d[1] = (bf16_t)v.y; d[2] = (bf16_t)v.z; d[3] = (bf16_t)v.w;
    }
    __syncthreads();

    const int wv = tid >> 6, lane = tid & 63;
    const int l16 = lane & 15, quad = lane >> 4;

    f32x4 acc[2][8];
#pragma unroll
    for (int r = 0; r < 2; r++)
#pragma unroll
        for (int c = 0; c < 8; c++) acc[r][c] = (f32x4){0.f, 0.f, 0.f, 0.f};

    {   // stage 1: K=32
        bf16x8 af0 = *(const bf16x8*)&T[(wv * 32 + l16) * S + quad * 8];
        bf16x8 af1 = *(const bf16x8*)&T[(wv * 32 + 16 + l16) * S + quad * 8];
#pragma unroll
        for (int c = 0; c < 8; c++) {
            bf16x8 bfr = *(const bf16x8*)&Ws1[((c * 64) + lane) * 8];
            acc[0][c] = MFMA16(af0, bfr, acc[0][c]);
            acc[1][c] = MFMA16(af1, bfr, acc[1][c]);
        }
    }
    __syncthreads();   // all A reads done; T becomes H

#pragma unroll
    for (int r = 0; r < 2; r++) {
        int mrow = wv * 32 + r * 16 + quad * 4;
#pragma unroll
        for (int c = 0; c < 8; c++) {
            int col = c * 16 + l16;
            float bb = bls1[col];
#pragma unroll
            for (int q = 0; q < 4; q++)
                T[(mrow + q) * S + col] = (bf16_t)fmaxf(acc[r][c][q] + bb, 0.f);
        }
    }
    __syncthreads();

#pragma unroll
    for (int r = 0; r < 2; r++)
#pragma unroll
        for (int c = 0; c < 8; c++) acc[r][c] = (f32x4){0.f, 0.f, 0.f, 0.f};

#pragma unroll
    for (int kc = 0; kc < 4; ++kc) {   // stage 2: K=128
        bf16x8 af0 = *(const bf16x8*)&T[(wv * 32 + l16) * S + kc * 32 + quad * 8];
        bf16x8 af1 = *(const bf16x8*)&T[(wv * 32 + 16 + l16) * S + kc * 32 + quad * 8];
#pragma unroll
        for (int c = 0; c < 8; c++) {
            bf16x8 bfr = *(const bf16x8*)&Ws2[(((kc * 8 + c) * 64) + lane) * 8];
            acc[0][c] = MFMA16(af0, bfr, acc[0][c]);
            acc[1][c] = MFMA16(af1, bfr, acc[1][c]);
        }
    }
    __syncthreads();   // all H reads done; T becomes Z

#pragma unroll
    for (int r = 0; r < 2; r++) {
        int mrow = wv * 32 + r * 16 + quad * 4;
#pragma unroll
        for (int c = 0; c < 8; c++) {
            int col = c * 16 + l16;
            float bb = bls2[col];
#pragma unroll
            for (int q = 0; q < 4; q++)
                T[(mrow + q) * S + col] = (bf16_t)(acc[r][c][q] + bb);
        }
    }
    __syncthreads();

    // coalesced scatter: 16 threads per 256B row, random row target
    for (int i = tid; i < 128 * 16; i += 256) {
        int row = i >> 4, seg = i & 15;
        if (row0 + row < M) {
            long prow = ranks[row];
            *(uint4*)&outp[prow * 128 + seg * 8] = *(const uint4*)&T[row * S + seg * 8];
        }
    }
}

// ---------------------------------------------------------------------------
// Fused GINEConv MLP: z = (relu(aggr @ W1 + b1)) @ W2 + b2 (z out bf16),
// + per-channel BN sum/sumsq. Union LDS A -> H -> Z, coalesced z write.
// ---------------------------------------------------------------------------
__global__ __launch_bounds__(256) void conv_fused_kernel(
    const float* __restrict__ A, int M,
    const bf16_t* __restrict__ Ws1, const float* __restrict__ b1,
    const bf16_t* __restrict__ Ws2, const float* __restrict__ b2,
    bf16_t* __restrict__ zout, float* __restrict__ bn_sums)
{
    constexpr int S = 136;
    __shared__ bf16_t T[128 * S];
    __shared__ float  bls1[128], bls2[128], bsum[128], bsq[128];

    const int  tid  = threadIdx.x;
    const long row0 = (long)blockIdx.x * 128;

    if (tid < 128) { bls1[tid] = b1[tid]; bls2[tid] = b2[tid]; bsum[tid] = 0.f; bsq[tid] = 0.f; }

    // stage A: 128 rows x 128 f32 -> bf16
    for (int i = tid; i < 128 * 32; i += 256) {
        int r = i / 32, c4 = (i % 32) * 4;
        long gr = row0 + r;
        float4 v = make_float4(0.f, 0.f, 0.f, 0.f);
        if (gr < M) v = *(const float4*)(A + gr * 128 + c4);
        bf16_t* d = &T[r * S + c4];
        d[0] = (bf16_t)v.x; d[1] = (bf16_t)v.y; d[2] = (bf16_t)v.z; d[3] = (bf16_t)v.w;
    }
    __syncthreads();

    const int wv = tid >> 6, lane = tid & 63;
    const int l16 = lane & 15, quad = lane >> 4;

    f32x4 acc[2][8];
#pragma unroll
    for (int r = 0; r < 2; r++)
#pragma unroll
        for (int c = 0; c < 8; c++) acc[r][c] = (f32x4){0.f, 0.f, 0.f, 0.f};

#pragma unroll
    for (int kc = 0; kc < 4; ++kc) {
        bf16x8 af0 = *(const bf16x8*)&T[(wv * 32 + l16) * S + kc * 32 + quad * 8];
        bf16x8 af1 = *(const bf16x8*)&T[(wv * 32 + 16 + l16) * S + kc * 32 + quad * 8];
#pragma unroll
        for (int c = 0; c < 8; c++) {
            bf16x8 bfr = *(const bf16x8*)&Ws1[(((kc * 8 + c) * 64) + lane) * 8];
            acc[0][c] = MFMA16(af0, bfr, acc[0][c]);
            acc[1][c] = MFMA16(af1, bfr, acc[1][c]);
        }
    }
    __syncthreads();   // A reads done; T becomes H

#pragma unroll
    for (int r = 0; r < 2; r++) {
        int mrow = wv * 32 + r * 16 + quad * 4;
#pragma unroll
        for (int c = 0; c < 8; c++) {
            int col = c * 16 + l16;
            float bb = bls1[col];
#pragma unroll
            for (int q = 0; q < 4; q++)
                T[(mrow + q) * S + col] = (bf16_t)fmaxf(acc[r][c][q] + bb, 0.f);
        }
    }
    __syncthreads();

#pragma unroll
    for (int r = 0; r < 2; r++)
#pragma unroll
        for (int c = 0; c < 8; c++) acc[r][c] = (f32x4){0.f, 0.f, 0.f, 0.f};

#pragma unroll
    for (int kc = 0; kc < 4; ++kc) {
        bf16x8 af0 = *(const bf16x8*)&T[(wv * 32 + l16) * S + kc * 32 + quad * 8];
        bf16x8 af1 = *(const bf16x8*)&T[(wv * 32 + 16 + l16) * S + kc * 32 + quad * 8];
#pragma unroll
        for (int c = 0; c < 8; c++) {
            bf16x8 bfr = *(const bf16x8*)&Ws2[(((kc * 8 + c) * 64) + lane) * 8];
            acc[0][c] = MFMA16(af0, bfr, acc[0][c]);
            acc[1][c] = MFMA16(af1, bfr, acc[1][c]);
        }
    }
    __syncthreads();   // H reads done; T becomes Z

#pragma unroll
    for (int r = 0; r < 2; r++) {
        int mrow = wv * 32 + r * 16 + quad * 4;
#pragma unroll
        for (int c = 0; c < 8; c++) {
            int col = c * 16 + l16;
            float bb = bls2[col];
#pragma unroll
            for (int q = 0; q < 4; q++) {
                long grow = row0 + mrow + q;
                float v = acc[r][c][q] + bb;
                T[(mrow + q) * S + col] = (bf16_t)v;
                if (grow < M) { atomicAdd(&bsum[col], v); atomicAdd(&bsq[col], v * v); }
            }
        }
    }
    __syncthreads();

    for (int i = tid; i < 128 * 16; i += 256) {
        int row = i >> 4, seg = i & 15;
        long grow = row0 + row;
        if (grow < M)
            *(uint4*)&zout[grow * 128 + seg * 8] = *(const uint4*)&T[row * S + seg * 8];
    }
    if (tid < 128) {
        atomicAdd(&bn_sums[tid], bsum[tid]);
        atomicAdd(&bn_sums[128 + tid], bsq[tid]);
    }
}

// ---------------------------------------------------------------------------
// CSR gather aggregation: aggr[n] = h[n] + sum relu(h[src] + e). 1 wave/node.
// ---------------------------------------------------------------------------
__global__ __launch_bounds__(256) void aggr_kernel(
    const float* __restrict__ h, const bf16_t* __restrict__ e,
    const int* __restrict__ rowptr, const int* __restrict__ srcp,
    float* __restrict__ aggr, int N)
{
    int wid = (int)(((long)blockIdx.x * 256 + threadIdx.x) >> 6);
    if (wid >= N) return;
    int lane = threadIdx.x & 63;
    const float2* hp = (const float2*)h;
    float2 acc = hp[(long)wid * 64 + lane];   // self term (eps=0)
    int beg = rowptr[wid], end = rowptr[wid + 1];
    int i = beg;
    for (; i + 1 < end; i += 2) {
        int s0 = srcp[i], s1 = srcp[i + 1];
        float2 h0 = hp[(long)s0 * 64 + lane];
        float2 h1 = hp[(long)s1 * 64 + lane];
        bf16x2 e0 = *(const bf16x2*)(e + (long)i * 128 + lane * 2);
        bf16x2 e1 = *(const bf16x2*)(e + ((long)i + 1) * 128 + lane * 2);
        acc.x += fmaxf(h0.x + (float)e0[0], 0.f);
        acc.y += fmaxf(h0.y + (float)e0[1], 0.f);
        acc.x += fmaxf(h1.x + (float)e1[0], 0.f);
        acc.y += fmaxf(h1.y + (float)e1[1], 0.f);
    }
    if (i < end) {
        int s0 = srcp[i];
        float2 h0 = hp[(long)s0 * 64 + lane];
        bf16x2 e0 = *(const bf16x2*)(e + (long)i * 128 + lane * 2);
        acc.x += fmaxf(h0.x + (float)e0[0], 0.f);
        acc.y += fmaxf(h0.y + (float)e0[1], 0.f);
    }
    ((float2*)aggr)[(long)wid * 64 + lane] = acc;
}

// ---------------------------------------------------------------------------
// BN finalize: scale/shift from accumulated sums; re-zeros sums for next layer.
// ---------------------------------------------------------------------------
__global__ void bn_fin_kernel(float* __restrict__ sums, const float* __restrict__ gamma,
                              const float* __restrict__ beta, float* __restrict__ scsh, int N)
{
    int c = threadIdx.x;
    float s  = sums[c];
    float sq = sums[128 + c];
    float mean = s / (float)N;
    float var  = sq / (float)N - mean * mean;
    float inv  = rsqrtf(var + 1e-5f);
    float sc   = gamma[c] * inv;
    scsh[c]       = sc;
    scsh[128 + c] = beta[c] - mean * sc;
    sums[c] = 0.f;
    sums[128 + c] = 0.f;
}

// BN apply + relu, vectorized: z bf16 in, h f32 out. total8 = N*128/8.
__global__ __launch_bounds__(256) void bn_apply_kernel(
    const bf16_t* __restrict__ z, const float* __restrict__ scsh,
    float* __restrict__ h, int total8)
{
    int idx = blockIdx.x * 256 + threadIdx.x;
    if (idx >= total8) return;
    long base = (long)idx * 8;
    int c0 = (int)(base & 127);
    bf16x8 zv = *(const bf16x8*)(z + base);
    float o[8];
#pragma unroll
    for (int j = 0; j < 8; j++)
        o[j] = fmaxf((float)zv[j] * scsh[c0 + j] + scsh[128 + c0 + j], 0.f);
    *(float4*)(h + base)     = make_float4(o[0], o[1], o[2], o[3]);
    *(float4*)(h + base + 4) = make_float4(o[4], o[5], o[6], o[7]);
}

// ---------------------------------------------------------------------------
__global__ __launch_bounds__(128) void pool_kernel(
    const float* __restrict__ h, const int* __restrict__ batch,
    float* __restrict__ gsum, float* __restrict__ cnt, int N)
{
    int c = threadIdx.x;
    int n0 = blockIdx.x * 256;
    int n1 = min(n0 + 256, N);
    float acc = 0.f;
    int cur = -1, rc = 0;
    for (int n = n0; n < n1; ++n) {
        int g = batch[n];
        if (g != cur) {
            if (cur >= 0) {
                atomicAdd(&gsum[(long)cur * 128 + c], acc);
                if (c == 0) atomicAdd(&cnt[cur], (float)rc);
            }
            cur = g; acc = 0.f; rc = 0;
        }
        acc += h[(long)n * 128 + c];
        rc++;
    }
    if (cur >= 0) {
        atomicAdd(&gsum[(long)cur * 128 + c], acc);
        if (c == 0) atomicAdd(&cnt[cur], (float)rc);
    }
}

__global__ __launch_bounds__(128) void head_kernel(
    const float* __restrict__ gsum, const float* __restrict__ cnt,
    const float* __restrict__ ext_in,
    const float* __restrict__ ew1, const float* __restrict__ eb1,
    const float* __restrict__ ew2, const float* __restrict__ eb2,
    const float* __restrict__ rw1, const float* __restrict__ rb1,
    const float* __restrict__ rw2, const float* __restrict__ rb2,
    float* __restrict__ out)
{
    int g = blockIdx.x, c = threadIdx.x;
    __shared__ float sx[8];
    __shared__ float h1[128];
    __shared__ float comb[256];
    __shared__ float red[128];

    if (c < 8) sx[c] = ext_in[g * 8 + c];
    __syncthreads();
    float a = eb1[c];
#pragma unroll
    for (int k = 0; k < 8; k++) a += sx[k] * ew1[k * 128 + c];
    h1[c] = fmaxf(a, 0.f);
    __syncthreads();
    float b = eb2[c];
    for (int k = 0; k < 128; k++) b += h1[k] * ew2[k * 128 + c];
    comb[c]       = gsum[(long)g * 128 + c] / fmaxf(cnt[g], 1.0f);
    comb[128 + c] = b;
    __syncthreads();
    float r = rb1[c];
    for (int k = 0; k < 256; k++) r += comb[k] * rw1[k * 128 + c];
    r = fmaxf(r, 0.f);
    red[c] = r * rw2[c];
    __syncthreads();
    if (c == 0) {
        float s = rb2[0];
        for (int k = 0; k < 128; k++) s += red[k];
        out[g] = s;
    }
}

// ---------------------------------------------------------------------------
extern "C" void kernel_launch(void* const* d_in, const int* in_sizes, int n_in,
                              void* d_out, int out_size, void* d_ws, size_t ws_size,
                              hipStream_t stream)
{
    const float* x         = (const float*)d_in[0];
    const float* edge_attr = (const float*)d_in[1];
    const float* externals = (const float*)d_in[2];
    const float* node_w    = (const float*)d_in[3];
    const float* node_b    = (const float*)d_in[4];
    const float* ee_w1     = (const float*)d_in[5];
    const float* ee_b1     = (const float*)d_in[6];
    const float* ee_w2     = (const float*)d_in[7];
    const float* ee_b2     = (const float*)d_in[8];
    const float* conv_w1   = (const float*)d_in[9];
    const float* conv_b1   = (const float*)d_in[10];
    const float* conv_w2   = (const float*)d_in[11];
    const float* conv_b2   = (const float*)d_in[12];
    const float* bn_gamma  = (const float*)d_in[13];
    const float* bn_beta   = (const float*)d_in[14];
    const float* ext_w1    = (const float*)d_in[15];
    const float* ext_b1    = (const float*)d_in[16];
    const float* ext_w2    = (const float*)d_in[17];
    const float* ext_b2    = (const float*)d_in[18];
    const float* reg_w1    = (const float*)d_in[19];
    const float* reg_b1    = (const float*)d_in[20];
    const float* reg_w2    = (const float*)d_in[21];
    const float* reg_b2    = (const float*)d_in[22];
    const int* edge_index  = (const int*)d_in[23];
    const int* batch       = (const int*)d_in[24];

    const int N = in_sizes[0] / 32;
    const int E = in_sizes[1] / 16;
    const int G = in_sizes[2] / 8;
    const int NB = (N + 1023) / 1024;

    char* p = (char*)d_ws;
    auto alloc = [&](size_t bytes) -> void* {
        void* r = (void*)p;
        p += (bytes + 255) & ~(size_t)255;
        return r;
    };
    float*  h       = (float*)alloc((size_t)N * 128 * sizeof(float));
    float*  aggr    = (float*)alloc((size_t)N * 128 * sizeof(float));
    bf16_t* zbuf    = (bf16_t*)alloc((size_t)N * 128 * sizeof(bf16_t));
    bf16_t* ebuf    = (bf16_t*)alloc((size_t)E * 128 * sizeof(bf16_t)); // dst-sorted
    int*    deg     = (int*)alloc((size_t)N * 4);
    int*    rowptr  = (int*)alloc(((size_t)N + 1) * 4);
    int*    cursor  = (int*)alloc((size_t)N * 4);
    int*    partials= (int*)alloc((size_t)N * 4);
    int*    bsums   = (int*)alloc((size_t)NB * 4);
    int*    boff    = (int*)alloc((size_t)NB * 4);
    int*    srcp    = (int*)alloc((size_t)E * 4);
    int*    rank    = (int*)alloc((size_t)E * 4);
    bf16_t* node_wt = (bf16_t*)alloc(128 * 32 * 2);
    bf16_t* ee_w1t  = (bf16_t*)alloc(128 * 32 * 2);
    bf16_t* ee_w2t  = (bf16_t*)alloc(128 * 128 * 2);
    bf16_t* cw1t    = (bf16_t*)alloc(3 * 128 * 128 * 2);
    bf16_t* cw2t    = (bf16_t*)alloc(3 * 128 * 128 * 2);
    float*  bn_sums = (float*)alloc(256 * 4);
    float*  scsh    = (float*)alloc(256 * 4);
    float*  gsum    = (float*)alloc((size_t)G * 128 * 4);
    float*  cnt     = (float*)alloc((size_t)G * 4);

    // --- CSR build (by dst) ---
    hipMemsetAsync(deg, 0, (size_t)N * 4, stream);
    hipMemsetAsync(bn_sums, 0, 256 * 4, stream);
    hist_kernel<<<(E + 255) / 256, 256, 0, stream>>>(edge_index, deg, E);
    scanA_kernel<<<NB, 256, 0, stream>>>(deg, partials, bsums, N);
    scanB_kernel<<<1, 256, 0, stream>>>(bsums, boff, rowptr, NB, N);
    scanC_kernel<<<(N + 255) / 256, 256, 0, stream>>>(partials, boff, rowptr, cursor, N);
    scatter_kernel<<<(E + 255) / 256, 256, 0, stream>>>(edge_index, cursor, srcp, rank, E);

    // --- weight prep ---
    prep_w_kernel<<<16, 256, 0, stream>>>(node_w, node_wt, 32, 32);
    prep_w_kernel<<<16, 256, 0, stream>>>(ee_w1, ee_w1t, 16, 32);
    prep_w_kernel<<<64, 256, 0, stream>>>(ee_w2, ee_w2t, 128, 128);
    for (int l = 0; l < 3; l++) {
        prep_w_kernel<<<64, 256, 0, stream>>>(conv_w1 + l * 16384, cw1t + l * 16384, 128, 128);
        prep_w_kernel<<<64, 256, 0, stream>>>(conv_w2 + l * 16384, cw2t + l * 16384, 128, 128);
    }

    // --- node encoder ---
    gemm32_kernel<<<(N + 127) / 128, 256, 0, stream>>>(x, N, 32, node_wt, node_b, h);

    // --- edge encoder -> ebuf in CSR order ---
    edge_mlp_kernel<<<(E + 127) / 128, 256, 0, stream>>>(
        edge_attr, E, ee_w1t, ee_b1, ee_w2t, ee_b2, rank, ebuf);

    // --- GINE layers ---
    const int total8 = N * 128 / 8;
    for (int l = 0; l < 3; l++) {
        aggr_kernel<<<(N + 3) / 4, 256, 0, stream>>>(h, ebuf, rowptr, srcp, aggr, N);
        conv_fused_kernel<<<(N + 127) / 128, 256, 0, stream>>>(
            aggr, N, cw1t + l * 16384, conv_b1 + l * 128,
            cw2t + l * 16384, conv_b2 + l * 128, zbuf, bn_sums);
        bn_fin_kernel<<<1, 128, 0, stream>>>(bn_sums, bn_gamma + l * 128, bn_beta + l * 128, scsh, N);
        bn_apply_kernel<<<(total8 + 255) / 256, 256, 0, stream>>>(zbuf, scsh, h, total8);
    }

    // --- pooling + head ---
    hipMemsetAsync(gsum, 0, (size_t)G * 128 * 4, stream);
    hipMemsetAsync(cnt, 0, (size_t)G * 4, stream);
    pool_kernel<<<(N + 255) / 256, 128, 0, stream>>>(h, batch, gsum, cnt, N);
    head_kernel<<<G, 128, 0, stream>>>(gsum, cnt, externals,
                                       ext_w1, ext_b1, ext_w2, ext_b2,
                                       reg_w1, reg_b1, reg_w2, reg_b2,
                                       (float*)d_out);
}

// Round 5
// 694.038 us; speedup vs baseline: 5.7318x; 1.4415x over previous
//
#include <hip/hip_runtime.h>

typedef __bf16 bf16_t;
typedef __bf16 bf16x8 __attribute__((ext_vector_type(8)));
typedef __bf16 bf16x4 __attribute__((ext_vector_type(4)));
typedef __bf16 bf16x2 __attribute__((ext_vector_type(2)));
typedef float  f32x4  __attribute__((ext_vector_type(4)));

#define MFMA16(a, b, c) __builtin_amdgcn_mfma_f32_16x16x32_bf16((a), (b), (c), 0, 0, 0)

// ---------------------------------------------------------------------------
// Weight prep: W [Kact,128] f32 row-major -> bf16 MFMA-B-fragment-sequential:
// idx = ((kc*8 + ctile)*64 + lane)*8 + j ; n = ctile*16+(lane&15),
// k = kc*32+(lane>>4)*8+j, zero-pad k>=Kact.
// ---------------------------------------------------------------------------
__global__ void prep_w_kernel(const float* __restrict__ W, bf16_t* __restrict__ Ws,
                              int Kact, int KP) {
    int idx = blockIdx.x * 256 + threadIdx.x;
    if (idx >= 128 * KP) return;
    int j    = idx & 7;
    int lane = (idx >> 3) & 63;
    int ct   = (idx >> 9) & 7;
    int kc   = idx >> 12;
    int n = ct * 16 + (lane & 15);
    int k = kc * 32 + (lane >> 4) * 8 + j;
    Ws[idx] = (bf16_t)((k < Kact) ? W[k * 128 + n] : 0.0f);
}

// ---------------------------------------------------------------------------
// CSR build: histogram of dst -> 3-phase device-wide scan -> scatter perm.
// ---------------------------------------------------------------------------
__global__ __launch_bounds__(256) void hist_kernel(const int* __restrict__ ei,
                                                   int* __restrict__ deg, int E) {
    int t = blockIdx.x * 256 + threadIdx.x;
    if (t < E) atomicAdd(&deg[ei[(long)E + t]], 1);
}

__global__ __launch_bounds__(256) void scanA_kernel(const int* __restrict__ deg,
                                                    int* __restrict__ partials,
                                                    int* __restrict__ bsums, int N) {
    __shared__ int s[256];
    int b = blockIdx.x, t = threadIdx.x;
    int base = b * 1024 + t * 4;
    int v0 = (base + 0 < N) ? deg[base + 0] : 0;
    int v1 = (base + 1 < N) ? deg[base + 1] : 0;
    int v2 = (base + 2 < N) ? deg[base + 2] : 0;
    int v3 = (base + 3 < N) ? deg[base + 3] : 0;
    int local = v0 + v1 + v2 + v3;
    s[t] = local;
    __syncthreads();
    for (int off = 1; off < 256; off <<= 1) {
        int v = (t >= off) ? s[t - off] : 0;
        __syncthreads();
        s[t] += v;
        __syncthreads();
    }
    int excl = s[t] - local;
    if (base + 0 < N) partials[base + 0] = excl;
    if (base + 1 < N) partials[base + 1] = excl + v0;
    if (base + 2 < N) partials[base + 2] = excl + v0 + v1;
    if (base + 3 < N) partials[base + 3] = excl + v0 + v1 + v2;
    if (t == 255) bsums[b] = s[255];
}

__global__ __launch_bounds__(256) void scanB_kernel(const int* __restrict__ bsums,
                                                    int* __restrict__ boff,
                                                    int* __restrict__ rowptr,
                                                    int NB, int N) {
    __shared__ int s[256];
    int t = threadIdx.x;
    int local = (t < NB) ? bsums[t] : 0;
    s[t] = local;
    __syncthreads();
    for (int off = 1; off < 256; off <<= 1) {
        int v = (t >= off) ? s[t - off] : 0;
        __syncthreads();
        s[t] += v;
        __syncthreads();
    }
    if (t < NB) boff[t] = s[t] - local;
    if (t == NB - 1) rowptr[N] = s[t];
}

__global__ __launch_bounds__(256) void scanC_kernel(const int* __restrict__ partials,
                                                    const int* __restrict__ boff,
                                                    int* __restrict__ rowptr,
                                                    int* __restrict__ cursor, int N) {
    int i = blockIdx.x * 256 + threadIdx.x;
    if (i >= N) return;
    int v = partials[i] + boff[i >> 10];
    rowptr[i] = v;
    cursor[i] = v;
}

__global__ __launch_bounds__(256) void scatter_kernel(const int* __restrict__ ei,
                                                      int* __restrict__ cursor,
                                                      int* __restrict__ srcp,
                                                      int* __restrict__ rank, int E) {
    int t = blockIdx.x * 256 + threadIdx.x;
    if (t >= E) return;
    int d = ei[(long)E + t];
    int pos = atomicAdd(&cursor[d], 1);
    srcp[pos] = ei[t];
    rank[t] = pos;
}

// ---------------------------------------------------------------------------
// Node encoder: h = x[M,32] @ W + bias, out bf16, LDS-roundtrip coalesced.
// ---------------------------------------------------------------------------
__global__ __launch_bounds__(256) void node_enc_kernel(
    const float* __restrict__ A, int M,
    const bf16_t* __restrict__ Ws, const float* __restrict__ bias,
    bf16_t* __restrict__ outp)
{
    constexpr int S = 136;
    __shared__ bf16_t T[128 * S];
    __shared__ float  bls[128];

    const int  tid  = threadIdx.x;
    const long row0 = (long)blockIdx.x * 128;

    if (tid < 128) bls[tid] = bias[tid];

    for (int i = tid; i < 128 * 8; i += 256) {
        int r = i / 8, c4 = (i % 8) * 4;
        long gr = row0 + r;
        float4 v = make_float4(0.f, 0.f, 0.f, 0.f);
        if (gr < M) v = *(const float4*)(A + gr * 32 + c4);
        bf16_t* d = &T[r * S + c4];
        d[0] = (bf16_t)v.x; d[1] = (bf16_t)v.y; d[2] = (bf16_t)v.z; d[3] = (bf16_t)v.w;
    }
    __syncthreads();

    const int wv = tid >> 6, lane = tid & 63;
    const int l16 = lane & 15, quad = lane >> 4;

    f32x4 acc[2][8];
#pragma unroll
    for (int r = 0; r < 2; r++)
#pragma unroll
        for (int c = 0; c < 8; c++) acc[r][c] = (f32x4){0.f, 0.f, 0.f, 0.f};

    {
        bf16x8 af0 = *(const bf16x8*)&T[(wv * 32 + l16) * S + quad * 8];
        bf16x8 af1 = *(const bf16x8*)&T[(wv * 32 + 16 + l16) * S + quad * 8];
#pragma unroll
        for (int c = 0; c < 8; c++) {
            bf16x8 bfr = *(const bf16x8*)&Ws[((c * 64) + lane) * 8];
            acc[0][c] = MFMA16(af0, bfr, acc[0][c]);
            acc[1][c] = MFMA16(af1, bfr, acc[1][c]);
        }
    }
    __syncthreads();   // T becomes Z

#pragma unroll
    for (int r = 0; r < 2; r++) {
        int mrow = wv * 32 + r * 16 + quad * 4;
#pragma unroll
        for (int c = 0; c < 8; c++) {
            int col = c * 16 + l16;
            float bb = bls[col];
#pragma unroll
            for (int q = 0; q < 4; q++)
                T[(mrow + q) * S + col] = (bf16_t)(acc[r][c][q] + bb);
        }
    }
    __syncthreads();

    for (int i = tid; i < 128 * 16; i += 256) {
        int row = i >> 4, seg = i & 15;
        long grow = row0 + row;
        if (grow < M)
            *(uint4*)&outp[grow * 128 + seg * 8] = *(const uint4*)&T[row * S + seg * 8];
    }
}

// ---------------------------------------------------------------------------
// Fused edge encoder: e = (relu(ea @ W1 + b1)) @ W2 + b2, rows written in
// dst-sorted (CSR) order via rank[]. Union LDS (A -> H -> Z), coalesced out.
// ---------------------------------------------------------------------------
__global__ __launch_bounds__(256) void edge_mlp_kernel(
    const float* __restrict__ A, int M,
    const bf16_t* __restrict__ Ws1, const float* __restrict__ b1,
    const bf16_t* __restrict__ Ws2, const float* __restrict__ b2,
    const int* __restrict__ rank, bf16_t* __restrict__ outp)
{
    constexpr int S = 136;
    __shared__ bf16_t T[128 * S];
    __shared__ float  bls1[128], bls2[128];
    __shared__ int    ranks[128];

    const int  tid  = threadIdx.x;
    const long row0 = (long)blockIdx.x * 128;

    if (tid < 128) {
        bls1[tid] = b1[tid];
        bls2[tid] = b2[tid];
        ranks[tid] = (row0 + tid < M) ? rank[row0 + tid] : 0;
    }

    for (int i = tid; i < 128 * 8; i += 256) {
        int r = i / 8, c4 = (i % 8) * 4;
        long gr = row0 + r;
        float4 v = make_float4(0.f, 0.f, 0.f, 0.f);
        if (gr < M && c4 < 16) v = *(const float4*)(A + gr * 16 + c4);
        bf16_t* d = &T[r * S + c4];
        d[0] = (bf16_t)v.x; d[1] = (bf16_t)v.y; d[2] = (bf16_t)v.z; d[3] = (bf16_t)v.w;
    }
    __syncthreads();

    const int wv = tid >> 6, lane = tid & 63;
    const int l16 = lane & 15, quad = lane >> 4;

    f32x4 acc[2][8];
#pragma unroll
    for (int r = 0; r < 2; r++)
#pragma unroll
        for (int c = 0; c < 8; c++) acc[r][c] = (f32x4){0.f, 0.f, 0.f, 0.f};

    {   // stage 1: K=32
        bf16x8 af0 = *(const bf16x8*)&T[(wv * 32 + l16) * S + quad * 8];
        bf16x8 af1 = *(const bf16x8*)&T[(wv * 32 + 16 + l16) * S + quad * 8];
#pragma unroll
        for (int c = 0; c < 8; c++) {
            bf16x8 bfr = *(const bf16x8*)&Ws1[((c * 64) + lane) * 8];
            acc[0][c] = MFMA16(af0, bfr, acc[0][c]);
            acc[1][c] = MFMA16(af1, bfr, acc[1][c]);
        }
    }
    __syncthreads();

#pragma unroll
    for (int r = 0; r < 2; r++) {
        int mrow = wv * 32 + r * 16 + quad * 4;
#pragma unroll
        for (int c = 0; c < 8; c++) {
            int col = c * 16 + l16;
            float bb = bls1[col];
#pragma unroll
            for (int q = 0; q < 4; q++)
                T[(mrow + q) * S + col] = (bf16_t)fmaxf(acc[r][c][q] + bb, 0.f);
        }
    }
    __syncthreads();

#pragma unroll
    for (int r = 0; r < 2; r++)
#pragma unroll
        for (int c = 0; c < 8; c++) acc[r][c] = (f32x4){0.f, 0.f, 0.f, 0.f};

#pragma unroll
    for (int kc = 0; kc < 4; ++kc) {   // stage 2: K=128
        bf16x8 af0 = *(const bf16x8*)&T[(wv * 32 + l16) * S + kc * 32 + quad * 8];
        bf16x8 af1 = *(const bf16x8*)&T[(wv * 32 + 16 + l16) * S + kc * 32 + quad * 8];
#pragma unroll
        for (int c = 0; c < 8; c++) {
            bf16x8 bfr = *(const bf16x8*)&Ws2[(((kc * 8 + c) * 64) + lane) * 8];
            acc[0][c] = MFMA16(af0, bfr, acc[0][c]);
            acc[1][c] = MFMA16(af1, bfr, acc[1][c]);
        }
    }
    __syncthreads();

#pragma unroll
    for (int r = 0; r < 2; r++) {
        int mrow = wv * 32 + r * 16 + quad * 4;
#pragma unroll
        for (int c = 0; c < 8; c++) {
            int col = c * 16 + l16;
            float bb = bls2[col];
#pragma unroll
            for (int q = 0; q < 4; q++)
                T[(mrow + q) * S + col] = (bf16_t)(acc[r][c][q] + bb);
        }
    }
    __syncthreads();

    for (int i = tid; i < 128 * 16; i += 256) {
        int row = i >> 4, seg = i & 15;
        if (row0 + row < M) {
            long prow = ranks[row];
            *(uint4*)&outp[prow * 128 + seg * 8] = *(const uint4*)&T[row * S + seg * 8];
        }
    }
}

// ---------------------------------------------------------------------------
// Fused GINEConv MLP: z = (relu(aggr @ W1 + b1)) @ W2 + b2 (bf16 in/out),
// BN sums via register butterfly reduction (quads) -> few LDS atomics.
// ---------------------------------------------------------------------------
__global__ __launch_bounds__(256) void conv_fused_kernel(
    const bf16_t* __restrict__ A, int M,
    const bf16_t* __restrict__ Ws1, const float* __restrict__ b1,
    const bf16_t* __restrict__ Ws2, const float* __restrict__ b2,
    bf16_t* __restrict__ zout, float* __restrict__ bn_sums)
{
    constexpr int S = 136;
    __shared__ bf16_t T[128 * S];
    __shared__ float  bls1[128], bls2[128], bsum[128], bsq[128];

    const int  tid  = threadIdx.x;
    const long row0 = (long)blockIdx.x * 128;

    if (tid < 128) { bls1[tid] = b1[tid]; bls2[tid] = b2[tid]; bsum[tid] = 0.f; bsq[tid] = 0.f; }

    // stage A: bf16 rows, pure uint4 copies
    for (int i = tid; i < 128 * 16; i += 256) {
        int r = i >> 4, seg = i & 15;
        long gr = row0 + r;
        uint4 v = make_uint4(0u, 0u, 0u, 0u);
        if (gr < M) v = *(const uint4*)(A + gr * 128 + seg * 8);
        *(uint4*)&T[r * S + seg * 8] = v;
    }
    __syncthreads();

    const int wv = tid >> 6, lane = tid & 63;
    const int l16 = lane & 15, quad = lane >> 4;

    f32x4 acc[2][8];
#pragma unroll
    for (int r = 0; r < 2; r++)
#pragma unroll
        for (int c = 0; c < 8; c++) acc[r][c] = (f32x4){0.f, 0.f, 0.f, 0.f};

#pragma unroll
    for (int kc = 0; kc < 4; ++kc) {
        bf16x8 af0 = *(const bf16x8*)&T[(wv * 32 + l16) * S + kc * 32 + quad * 8];
        bf16x8 af1 = *(const bf16x8*)&T[(wv * 32 + 16 + l16) * S + kc * 32 + quad * 8];
#pragma unroll
        for (int c = 0; c < 8; c++) {
            bf16x8 bfr = *(const bf16x8*)&Ws1[(((kc * 8 + c) * 64) + lane) * 8];
            acc[0][c] = MFMA16(af0, bfr, acc[0][c]);
            acc[1][c] = MFMA16(af1, bfr, acc[1][c]);
        }
    }
    __syncthreads();   // T becomes H

#pragma unroll
    for (int r = 0; r < 2; r++) {
        int mrow = wv * 32 + r * 16 + quad * 4;
#pragma unroll
        for (int c = 0; c < 8; c++) {
            int col = c * 16 + l16;
            float bb = bls1[col];
#pragma unroll
            for (int q = 0; q < 4; q++)
                T[(mrow + q) * S + col] = (bf16_t)fmaxf(acc[r][c][q] + bb, 0.f);
        }
    }
    __syncthreads();

#pragma unroll
    for (int r = 0; r < 2; r++)
#pragma unroll
        for (int c = 0; c < 8; c++) acc[r][c] = (f32x4){0.f, 0.f, 0.f, 0.f};

#pragma unroll
    for (int kc = 0; kc < 4; ++kc) {
        bf16x8 af0 = *(const bf16x8*)&T[(wv * 32 + l16) * S + kc * 32 + quad * 8];
        bf16x8 af1 = *(const bf16x8*)&T[(wv * 32 + 16 + l16) * S + kc * 32 + quad * 8];
#pragma unroll
        for (int c = 0; c < 8; c++) {
            bf16x8 bfr = *(const bf16x8*)&Ws2[(((kc * 8 + c) * 64) + lane) * 8];
            acc[0][c] = MFMA16(af0, bfr, acc[0][c]);
            acc[1][c] = MFMA16(af1, bfr, acc[1][c]);
        }
    }
    __syncthreads();   // T becomes Z

#pragma unroll
    for (int c = 0; c < 8; c++) {
        int col = c * 16 + l16;
        float bb = bls2[col];
        float s = 0.f, s2 = 0.f;
#pragma unroll
        for (int r = 0; r < 2; r++) {
            int mrow = wv * 32 + r * 16 + quad * 4;
#pragma unroll
            for (int q = 0; q < 4; q++) {
                float v = acc[r][c][q] + bb;
                T[(mrow + q) * S + col] = (bf16_t)v;
                if (row0 + mrow + q < M) { s += v; s2 += v * v; }
            }
        }
        // reduce across the 4 quads holding the same column
        s  += __shfl_xor(s, 16);  s  += __shfl_xor(s, 32);
        s2 += __shfl_xor(s2, 16); s2 += __shfl_xor(s2, 32);
        if (quad == 0) { atomicAdd(&bsum[col], s); atomicAdd(&bsq[col], s2); }
    }
    __syncthreads();

    for (int i = tid; i < 128 * 16; i += 256) {
        int row = i >> 4, seg = i & 15;
        long grow = row0 + row;
        if (grow < M)
            *(uint4*)&zout[grow * 128 + seg * 8] = *(const uint4*)&T[row * S + seg * 8];
    }
    if (tid < 128) {
        atomicAdd(&bn_sums[tid], bsum[tid]);
        atomicAdd(&bn_sums[128 + tid], bsq[tid]);
    }
}

// ---------------------------------------------------------------------------
// CSR gather aggregation: aggr[n] = h[n] + sum relu(h[src] + e). 1 wave/node,
// h/e/aggr all bf16, 2 channels per lane.
// ---------------------------------------------------------------------------
__global__ __launch_bounds__(256) void aggr_kernel(
    const bf16_t* __restrict__ h, const bf16_t* __restrict__ e,
    const int* __restrict__ rowptr, const int* __restrict__ srcp,
    bf16_t* __restrict__ aggr, int N)
{
    int wid = (int)(((long)blockIdx.x * 256 + threadIdx.x) >> 6);
    if (wid >= N) return;
    int lane = threadIdx.x & 63;
    bf16x2 hv = *(const bf16x2*)(h + (long)wid * 128 + lane * 2);
    float ax = (float)hv[0], ay = (float)hv[1];   // self term (eps=0)
    int beg = rowptr[wid], end = rowptr[wid + 1];
    int i = beg;
    for (; i + 1 < end; i += 2) {
        int s0 = srcp[i], s1 = srcp[i + 1];
        bf16x2 h0 = *(const bf16x2*)(h + (long)s0 * 128 + lane * 2);
        bf16x2 h1 = *(const bf16x2*)(h + (long)s1 * 128 + lane * 2);
        bf16x2 e0 = *(const bf16x2*)(e + (long)i * 128 + lane * 2);
        bf16x2 e1 = *(const bf16x2*)(e + ((long)i + 1) * 128 + lane * 2);
        ax += fmaxf((float)h0[0] + (float)e0[0], 0.f);
        ay += fmaxf((float)h0[1] + (float)e0[1], 0.f);
        ax += fmaxf((float)h1[0] + (float)e1[0], 0.f);
        ay += fmaxf((float)h1[1] + (float)e1[1], 0.f);
    }
    if (i < end) {
        int s0 = srcp[i];
        bf16x2 h0 = *(const bf16x2*)(h + (long)s0 * 128 + lane * 2);
        bf16x2 e0 = *(const bf16x2*)(e + (long)i * 128 + lane * 2);
        ax += fmaxf((float)h0[0] + (float)e0[0], 0.f);
        ay += fmaxf((float)h0[1] + (float)e0[1], 0.f);
    }
    bf16x2 o; o[0] = (bf16_t)ax; o[1] = (bf16_t)ay;
    *(bf16x2*)(aggr + (long)wid * 128 + lane * 2) = o;
}

// ---------------------------------------------------------------------------
__global__ void bn_fin_kernel(float* __restrict__ sums, const float* __restrict__ gamma,
                              const float* __restrict__ beta, float* __restrict__ scsh, int N)
{
    int c = threadIdx.x;
    float s  = sums[c];
    float sq = sums[128 + c];
    float mean = s / (float)N;
    float var  = sq / (float)N - mean * mean;
    float inv  = rsqrtf(var + 1e-5f);
    float sc   = gamma[c] * inv;
    scsh[c]       = sc;
    scsh[128 + c] = beta[c] - mean * sc;
    sums[c] = 0.f;
    sums[128 + c] = 0.f;
}

// BN apply + relu: z bf16 in, h bf16 out, 8 elems/thread.
__global__ __launch_bounds__(256) void bn_apply_kernel(
    const bf16_t* __restrict__ z, const float* __restrict__ scsh,
    bf16_t* __restrict__ h, int total8)
{
    int idx = blockIdx.x * 256 + threadIdx.x;
    if (idx >= total8) return;
    long base = (long)idx * 8;
    int c0 = (int)(base & 127);
    bf16x8 zv = *(const bf16x8*)(z + base);
    bf16x8 hv;
#pragma unroll
    for (int j = 0; j < 8; j++)
        hv[j] = (bf16_t)fmaxf((float)zv[j] * scsh[c0 + j] + scsh[128 + c0 + j], 0.f);
    *(bf16x8*)(h + base) = hv;
}

// ---------------------------------------------------------------------------
__global__ __launch_bounds__(128) void pool_kernel(
    const bf16_t* __restrict__ h, const int* __restrict__ batch,
    float* __restrict__ gsum, float* __restrict__ cnt, int N)
{
    int c = threadIdx.x;
    int n0 = blockIdx.x * 256;
    int n1 = min(n0 + 256, N);
    float acc = 0.f;
    int cur = -1, rc = 0;
    for (int n = n0; n < n1; ++n) {
        int g = batch[n];
        if (g != cur) {
            if (cur >= 0) {
                atomicAdd(&gsum[(long)cur * 128 + c], acc);
                if (c == 0) atomicAdd(&cnt[cur], (float)rc);
            }
            cur = g; acc = 0.f; rc = 0;
        }
        acc += (float)h[(long)n * 128 + c];
        rc++;
    }
    if (cur >= 0) {
        atomicAdd(&gsum[(long)cur * 128 + c], acc);
        if (c == 0) atomicAdd(&cnt[cur], (float)rc);
    }
}

__global__ __launch_bounds__(128) void head_kernel(
    const float* __restrict__ gsum, const float* __restrict__ cnt,
    const float* __restrict__ ext_in,
    const float* __restrict__ ew1, const float* __restrict__ eb1,
    const float* __restrict__ ew2, const float* __restrict__ eb2,
    const float* __restrict__ rw1, const float* __restrict__ rb1,
    const float* __restrict__ rw2, const float* __restrict__ rb2,
    float* __restrict__ out)
{
    int g = blockIdx.x, c = threadIdx.x;
    __shared__ float sx[8];
    __shared__ float h1[128];
    __shared__ float comb[256];
    __shared__ float red[128];

    if (c < 8) sx[c] = ext_in[g * 8 + c];
    __syncthreads();
    float a = eb1[c];
#pragma unroll
    for (int k = 0; k < 8; k++) a += sx[k] * ew1[k * 128 + c];
    h1[c] = fmaxf(a, 0.f);
    __syncthreads();
    float b = eb2[c];
    for (int k = 0; k < 128; k++) b += h1[k] * ew2[k * 128 + c];
    comb[c]       = gsum[(long)g * 128 + c] / fmaxf(cnt[g], 1.0f);
    comb[128 + c] = b;
    __syncthreads();
    float r = rb1[c];
    for (int k = 0; k < 256; k++) r += comb[k] * rw1[k * 128 + c];
    r = fmaxf(r, 0.f);
    red[c] = r * rw2[c];
    __syncthreads();
    if (c == 0) {
        float s = rb2[0];
        for (int k = 0; k < 128; k++) s += red[k];
        out[g] = s;
    }
}

// ---------------------------------------------------------------------------
extern "C" void kernel_launch(void* const* d_in, const int* in_sizes, int n_in,
                              void* d_out, int out_size, void* d_ws, size_t ws_size,
                              hipStream_t stream)
{
    const float* x         = (const float*)d_in[0];
    const float* edge_attr = (const float*)d_in[1];
    const float* externals = (const float*)d_in[2];
    const float* node_w    = (const float*)d_in[3];
    const float* node_b    = (const float*)d_in[4];
    const float* ee_w1     = (const float*)d_in[5];
    const float* ee_b1     = (const float*)d_in[6];
    const float* ee_w2     = (const float*)d_in[7];
    const float* ee_b2     = (const float*)d_in[8];
    const float* conv_w1   = (const float*)d_in[9];
    const float* conv_b1   = (const float*)d_in[10];
    const float* conv_w2   = (const float*)d_in[11];
    const float* conv_b2   = (const float*)d_in[12];
    const float* bn_gamma  = (const float*)d_in[13];
    const float* bn_beta   = (const float*)d_in[14];
    const float* ext_w1    = (const float*)d_in[15];
    const float* ext_b1    = (const float*)d_in[16];
    const float* ext_w2    = (const float*)d_in[17];
    const float* ext_b2    = (const float*)d_in[18];
    const float* reg_w1    = (const float*)d_in[19];
    const float* reg_b1    = (const float*)d_in[20];
    const float* reg_w2    = (const float*)d_in[21];
    const float* reg_b2    = (const float*)d_in[22];
    const int* edge_index  = (const int*)d_in[23];
    const int* batch       = (const int*)d_in[24];

    const int N = in_sizes[0] / 32;
    const int E = in_sizes[1] / 16;
    const int G = in_sizes[2] / 8;
    const int NB = (N + 1023) / 1024;

    char* p = (char*)d_ws;
    auto alloc = [&](size_t bytes) -> void* {
        void* r = (void*)p;
        p += (bytes + 255) & ~(size_t)255;
        return r;
    };
    bf16_t* h       = (bf16_t*)alloc((size_t)N * 128 * 2);
    bf16_t* aggr    = (bf16_t*)alloc((size_t)N * 128 * 2);
    bf16_t* zbuf    = (bf16_t*)alloc((size_t)N * 128 * 2);
    bf16_t* ebuf    = (bf16_t*)alloc((size_t)E * 128 * 2);   // dst-sorted
    int*    deg     = (int*)alloc((size_t)N * 4);
    int*    rowptr  = (int*)alloc(((size_t)N + 1) * 4);
    int*    cursor  = (int*)alloc((size_t)N * 4);
    int*    partials= (int*)alloc((size_t)N * 4);
    int*    bsums   = (int*)alloc((size_t)NB * 4);
    int*    boff    = (int*)alloc((size_t)NB * 4);
    int*    srcp    = (int*)alloc((size_t)E * 4);
    int*    rank    = (int*)alloc((size_t)E * 4);
    bf16_t* node_wt = (bf16_t*)alloc(128 * 32 * 2);
    bf16_t* ee_w1t  = (bf16_t*)alloc(128 * 32 * 2);
    bf16_t* ee_w2t  = (bf16_t*)alloc(128 * 128 * 2);
    bf16_t* cw1t    = (bf16_t*)alloc(3 * 128 * 128 * 2);
    bf16_t* cw2t    = (bf16_t*)alloc(3 * 128 * 128 * 2);
    float*  bn_sums = (float*)alloc(256 * 4);
    float*  scsh    = (float*)alloc(256 * 4);
    float*  gsum    = (float*)alloc((size_t)G * 128 * 4);
    float*  cnt     = (float*)alloc((size_t)G * 4);

    // --- CSR build (by dst) ---
    hipMemsetAsync(deg, 0, (size_t)N * 4, stream);
    hipMemsetAsync(bn_sums, 0, 256 * 4, stream);
    hist_kernel<<<(E + 255) / 256, 256, 0, stream>>>(edge_index, deg, E);
    scanA_kernel<<<NB, 256, 0, stream>>>(deg, partials, bsums, N);
    scanB_kernel<<<1, 256, 0, stream>>>(bsums, boff, rowptr, NB, N);
    scanC_kernel<<<(N + 255) / 256, 256, 0, stream>>>(partials, boff, rowptr, cursor, N);
    scatter_kernel<<<(E + 255) / 256, 256, 0, stream>>>(edge_index, cursor, srcp, rank, E);

    // --- weight prep ---
    prep_w_kernel<<<16, 256, 0, stream>>>(node_w, node_wt, 32, 32);
    prep_w_kernel<<<16, 256, 0, stream>>>(ee_w1, ee_w1t, 16, 32);
    prep_w_kernel<<<64, 256, 0, stream>>>(ee_w2, ee_w2t, 128, 128);
    for (int l = 0; l < 3; l++) {
        prep_w_kernel<<<64, 256, 0, stream>>>(conv_w1 + l * 16384, cw1t + l * 16384, 128, 128);
        prep_w_kernel<<<64, 256, 0, stream>>>(conv_w2 + l * 16384, cw2t + l * 16384, 128, 128);
    }

    // --- node encoder ---
    node_enc_kernel<<<(N + 127) / 128, 256, 0, stream>>>(x, N, node_wt, node_b, h);

    // --- edge encoder -> ebuf in CSR order ---
    edge_mlp_kernel<<<(E + 127) / 128, 256, 0, stream>>>(
        edge_attr, E, ee_w1t, ee_b1, ee_w2t, ee_b2, rank, ebuf);

    // --- GINE layers ---
    const int total8 = N * 128 / 8;
    for (int l = 0; l < 3; l++) {
        aggr_kernel<<<(N + 3) / 4, 256, 0, stream>>>(h, ebuf, rowptr, srcp, aggr, N);
        conv_fused_kernel<<<(N + 127) / 128, 256, 0, stream>>>(
            aggr, N, cw1t + l * 16384, conv_b1 + l * 128,
            cw2t + l * 16384, conv_b2 + l * 128, zbuf, bn_sums);
        bn_fin_kernel<<<1, 128, 0, stream>>>(bn_sums, bn_gamma + l * 128, bn_beta + l * 128, scsh, N);
        bn_apply_kernel<<<(total8 + 255) / 256, 256, 0, stream>>>(zbuf, scsh, h, total8);
    }

    // --- pooling + head ---
    hipMemsetAsync(gsum, 0, (size_t)G * 128 * 4, stream);
    hipMemsetAsync(cnt, 0, (size_t)G * 4, stream);
    pool_kernel<<<(N + 255) / 256, 128, 0, stream>>>(h, batch, gsum, cnt, N);
    head_kernel<<<G, 128, 0, stream>>>(gsum, cnt, externals,
                                       ext_w1, ext_b1, ext_w2, ext_b2,
                                       reg_w1, reg_b1, reg_w2, reg_b2,
                                       (float*)d_out);
}

// Round 6
// 685.348 us; speedup vs baseline: 5.8045x; 1.0127x over previous
//
#include <hip/hip_runtime.h>

typedef __bf16 bf16_t;
typedef __bf16 bf16x8 __attribute__((ext_vector_type(8)));
typedef __bf16 bf16x4 __attribute__((ext_vector_type(4)));
typedef __bf16 bf16x2 __attribute__((ext_vector_type(2)));
typedef float  f32x4  __attribute__((ext_vector_type(4)));

#define MFMA16(a, b, c) __builtin_amdgcn_mfma_f32_16x16x32_bf16((a), (b), (c), 0, 0, 0)

// ---------------------------------------------------------------------------
// Weight prep: W [Kact,128] f32 row-major -> bf16 MFMA-B-fragment-sequential:
// idx = ((kc*8 + ctile)*64 + lane)*8 + j ; n = ctile*16+(lane&15),
// k = kc*32+(lane>>4)*8+j, zero-pad k>=Kact.
// ---------------------------------------------------------------------------
__global__ void prep_w_kernel(const float* __restrict__ W, bf16_t* __restrict__ Ws,
                              int Kact, int KP) {
    int idx = blockIdx.x * 256 + threadIdx.x;
    if (idx >= 128 * KP) return;
    int j    = idx & 7;
    int lane = (idx >> 3) & 63;
    int ct   = (idx >> 9) & 7;
    int kc   = idx >> 12;
    int n = ct * 16 + (lane & 15);
    int k = kc * 32 + (lane >> 4) * 8 + j;
    Ws[idx] = (bf16_t)((k < Kact) ? W[k * 128 + n] : 0.0f);
}

// ---------------------------------------------------------------------------
// CSR build: histogram of dst -> 3-phase device-wide scan -> scatter perm.
// eorig[pos] = original edge index (inverse permutation for gather-in).
// ---------------------------------------------------------------------------
__global__ __launch_bounds__(256) void hist_kernel(const int* __restrict__ ei,
                                                   int* __restrict__ deg, int E) {
    int t = blockIdx.x * 256 + threadIdx.x;
    if (t < E) atomicAdd(&deg[ei[(long)E + t]], 1);
}

__global__ __launch_bounds__(256) void scanA_kernel(const int* __restrict__ deg,
                                                    int* __restrict__ partials,
                                                    int* __restrict__ bsums, int N) {
    __shared__ int s[256];
    int b = blockIdx.x, t = threadIdx.x;
    int base = b * 1024 + t * 4;
    int v0 = (base + 0 < N) ? deg[base + 0] : 0;
    int v1 = (base + 1 < N) ? deg[base + 1] : 0;
    int v2 = (base + 2 < N) ? deg[base + 2] : 0;
    int v3 = (base + 3 < N) ? deg[base + 3] : 0;
    int local = v0 + v1 + v2 + v3;
    s[t] = local;
    __syncthreads();
    for (int off = 1; off < 256; off <<= 1) {
        int v = (t >= off) ? s[t - off] : 0;
        __syncthreads();
        s[t] += v;
        __syncthreads();
    }
    int excl = s[t] - local;
    if (base + 0 < N) partials[base + 0] = excl;
    if (base + 1 < N) partials[base + 1] = excl + v0;
    if (base + 2 < N) partials[base + 2] = excl + v0 + v1;
    if (base + 3 < N) partials[base + 3] = excl + v0 + v1 + v2;
    if (t == 255) bsums[b] = s[255];
}

__global__ __launch_bounds__(256) void scanB_kernel(const int* __restrict__ bsums,
                                                    int* __restrict__ boff,
                                                    int* __restrict__ rowptr,
                                                    int NB, int N) {
    __shared__ int s[256];
    int t = threadIdx.x;
    int local = (t < NB) ? bsums[t] : 0;
    s[t] = local;
    __syncthreads();
    for (int off = 1; off < 256; off <<= 1) {
        int v = (t >= off) ? s[t - off] : 0;
        __syncthreads();
        s[t] += v;
        __syncthreads();
    }
    if (t < NB) boff[t] = s[t] - local;
    if (t == NB - 1) rowptr[N] = s[t];
}

__global__ __launch_bounds__(256) void scanC_kernel(const int* __restrict__ partials,
                                                    const int* __restrict__ boff,
                                                    int* __restrict__ rowptr,
                                                    int* __restrict__ cursor, int N) {
    int i = blockIdx.x * 256 + threadIdx.x;
    if (i >= N) return;
    int v = partials[i] + boff[i >> 10];
    rowptr[i] = v;
    cursor[i] = v;
}

__global__ __launch_bounds__(256) void scatter_kernel(const int* __restrict__ ei,
                                                      int* __restrict__ cursor,
                                                      int* __restrict__ srcp,
                                                      int* __restrict__ eorig, int E) {
    int t = blockIdx.x * 256 + threadIdx.x;
    if (t >= E) return;
    int d = ei[(long)E + t];
    int pos = atomicAdd(&cursor[d], 1);
    srcp[pos] = ei[t];
    eorig[pos] = t;
}

// ---------------------------------------------------------------------------
// Node encoder: h = x[M,32] @ W + bias, out bf16, LDS-roundtrip coalesced.
// ---------------------------------------------------------------------------
__global__ __launch_bounds__(256) void node_enc_kernel(
    const float* __restrict__ A, int M,
    const bf16_t* __restrict__ Ws, const float* __restrict__ bias,
    bf16_t* __restrict__ outp)
{
    constexpr int S = 136;
    __shared__ bf16_t T[128 * S];
    __shared__ float  bls[128];

    const int  tid  = threadIdx.x;
    const long row0 = (long)blockIdx.x * 128;

    if (tid < 128) bls[tid] = bias[tid];

    for (int i = tid; i < 128 * 8; i += 256) {
        int r = i / 8, c4 = (i % 8) * 4;
        long gr = row0 + r;
        float4 v = make_float4(0.f, 0.f, 0.f, 0.f);
        if (gr < M) v = *(const float4*)(A + gr * 32 + c4);
        bf16_t* d = &T[r * S + c4];
        d[0] = (bf16_t)v.x; d[1] = (bf16_t)v.y; d[2] = (bf16_t)v.z; d[3] = (bf16_t)v.w;
    }
    __syncthreads();

    const int wv = tid >> 6, lane = tid & 63;
    const int l16 = lane & 15, quad = lane >> 4;

    f32x4 acc[2][8];
#pragma unroll
    for (int r = 0; r < 2; r++)
#pragma unroll
        for (int c = 0; c < 8; c++) acc[r][c] = (f32x4){0.f, 0.f, 0.f, 0.f};

    {
        bf16x8 af0 = *(const bf16x8*)&T[(wv * 32 + l16) * S + quad * 8];
        bf16x8 af1 = *(const bf16x8*)&T[(wv * 32 + 16 + l16) * S + quad * 8];
#pragma unroll
        for (int c = 0; c < 8; c++) {
            bf16x8 bfr = *(const bf16x8*)&Ws[((c * 64) + lane) * 8];
            acc[0][c] = MFMA16(af0, bfr, acc[0][c]);
            acc[1][c] = MFMA16(af1, bfr, acc[1][c]);
        }
    }
    __syncthreads();   // T becomes Z

#pragma unroll
    for (int r = 0; r < 2; r++) {
        int mrow = wv * 32 + r * 16 + quad * 4;
#pragma unroll
        for (int c = 0; c < 8; c++) {
            int col = c * 16 + l16;
            float bb = bls[col];
#pragma unroll
            for (int q = 0; q < 4; q++)
                T[(mrow + q) * S + col] = (bf16_t)(acc[r][c][q] + bb);
        }
    }
    __syncthreads();

    for (int i = tid; i < 128 * 16; i += 256) {
        int row = i >> 4, seg = i & 15;
        long grow = row0 + row;
        if (grow < M)
            *(uint4*)&outp[grow * 128 + seg * 8] = *(const uint4*)&T[row * S + seg * 8];
    }
}

// ---------------------------------------------------------------------------
// Fused edge encoder, CSR-ORDER COMPUTE: output row p (CSR position) is
// edge eorig[p]; inputs gathered from edge_attr (L3-resident), output written
// SEQUENTIALLY. Union LDS (A -> H -> Z).
// ---------------------------------------------------------------------------
__global__ __launch_bounds__(256) void edge_mlp_kernel(
    const float* __restrict__ A, int M,
    const bf16_t* __restrict__ Ws1, const float* __restrict__ b1,
    const bf16_t* __restrict__ Ws2, const float* __restrict__ b2,
    const int* __restrict__ eorig, bf16_t* __restrict__ outp)
{
    constexpr int S = 136;
    __shared__ bf16_t T[128 * S];
    __shared__ float  bls1[128], bls2[128];
    __shared__ int    eors[128];

    const int  tid  = threadIdx.x;
    const long row0 = (long)blockIdx.x * 128;

    if (tid < 128) {
        bls1[tid] = b1[tid];
        bls2[tid] = b2[tid];
        eors[tid] = (row0 + tid < M) ? eorig[row0 + tid] : 0;
    }
    __syncthreads();

    // stage A: gather 128 rows x 16 f32 by eors (pad cols 16..31 with zeros)
    for (int i = tid; i < 128 * 8; i += 256) {
        int r = i / 8, c4 = (i % 8) * 4;
        float4 v = make_float4(0.f, 0.f, 0.f, 0.f);
        if (row0 + r < M && c4 < 16) v = *(const float4*)(A + (long)eors[r] * 16 + c4);
        bf16_t* d = &T[r * S + c4];
        d[0] = (bf16_t)v.x; d[1] = (bf16_t)v.y; d[2] = (bf16_t)v.z; d[3] = (bf16_t)v.w;
    }
    __syncthreads();

    const int wv = tid >> 6, lane = tid & 63;
    const int l16 = lane & 15, quad = lane >> 4;

    f32x4 acc[2][8];
#pragma unroll
    for (int r = 0; r < 2; r++)
#pragma unroll
        for (int c = 0; c < 8; c++) acc[r][c] = (f32x4){0.f, 0.f, 0.f, 0.f};

    {   // stage 1: K=32
        bf16x8 af0 = *(const bf16x8*)&T[(wv * 32 + l16) * S + quad * 8];
        bf16x8 af1 = *(const bf16x8*)&T[(wv * 32 + 16 + l16) * S + quad * 8];
#pragma unroll
        for (int c = 0; c < 8; c++) {
            bf16x8 bfr = *(const bf16x8*)&Ws1[((c * 64) + lane) * 8];
            acc[0][c] = MFMA16(af0, bfr, acc[0][c]);
            acc[1][c] = MFMA16(af1, bfr, acc[1][c]);
        }
    }
    __syncthreads();

#pragma unroll
    for (int r = 0; r < 2; r++) {
        int mrow = wv * 32 + r * 16 + quad * 4;
#pragma unroll
        for (int c = 0; c < 8; c++) {
            int col = c * 16 + l16;
            float bb = bls1[col];
#pragma unroll
            for (int q = 0; q < 4; q++)
                T[(mrow + q) * S + col] = (bf16_t)fmaxf(acc[r][c][q] + bb, 0.f);
        }
    }
    __syncthreads();

#pragma unroll
    for (int r = 0; r < 2; r++)
#pragma unroll
        for (int c = 0; c < 8; c++) acc[r][c] = (f32x4){0.f, 0.f, 0.f, 0.f};

#pragma unroll
    for (int kc = 0; kc < 4; ++kc) {   // stage 2: K=128
        bf16x8 af0 = *(const bf16x8*)&T[(wv * 32 + l16) * S + kc * 32 + quad * 8];
        bf16x8 af1 = *(const bf16x8*)&T[(wv * 32 + 16 + l16) * S + kc * 32 + quad * 8];
#pragma unroll
        for (int c = 0; c < 8; c++) {
            bf16x8 bfr = *(const bf16x8*)&Ws2[(((kc * 8 + c) * 64) + lane) * 8];
            acc[0][c] = MFMA16(af0, bfr, acc[0][c]);
            acc[1][c] = MFMA16(af1, bfr, acc[1][c]);
        }
    }
    __syncthreads();

#pragma unroll
    for (int r = 0; r < 2; r++) {
        int mrow = wv * 32 + r * 16 + quad * 4;
#pragma unroll
        for (int c = 0; c < 8; c++) {
            int col = c * 16 + l16;
            float bb = bls2[col];
#pragma unroll
            for (int q = 0; q < 4; q++)
                T[(mrow + q) * S + col] = (bf16_t)(acc[r][c][q] + bb);
        }
    }
    __syncthreads();

    // sequential coalesced output
    for (int i = tid; i < 128 * 16; i += 256) {
        int row = i >> 4, seg = i & 15;
        long grow = row0 + row;
        if (grow < M)
            *(uint4*)&outp[grow * 128 + seg * 8] = *(const uint4*)&T[row * S + seg * 8];
    }
}

// ---------------------------------------------------------------------------
// Fused GINEConv MLP, 64-row tiles (2x grid, lighter LDS/regs):
// z = (relu(aggr @ W1 + b1)) @ W2 + b2 (bf16 in/out), BN sums via butterfly.
// ---------------------------------------------------------------------------
__global__ __launch_bounds__(256) void conv_fused_kernel(
    const bf16_t* __restrict__ A, int M,
    const bf16_t* __restrict__ Ws1, const float* __restrict__ b1,
    const bf16_t* __restrict__ Ws2, const float* __restrict__ b2,
    bf16_t* __restrict__ zout, float* __restrict__ bn_sums)
{
    constexpr int S = 136;
    __shared__ bf16_t T[64 * S];    // 17.4 KB
    __shared__ float  bls1[128], bls2[128], bsum[128], bsq[128];

    const int  tid  = threadIdx.x;
    const long row0 = (long)blockIdx.x * 64;

    if (tid < 128) { bls1[tid] = b1[tid]; bls2[tid] = b2[tid]; bsum[tid] = 0.f; bsq[tid] = 0.f; }

    for (int i = tid; i < 64 * 16; i += 256) {
        int r = i >> 4, seg = i & 15;
        long gr = row0 + r;
        uint4 v = make_uint4(0u, 0u, 0u, 0u);
        if (gr < M) v = *(const uint4*)(A + gr * 128 + seg * 8);
        *(uint4*)&T[r * S + seg * 8] = v;
    }
    __syncthreads();

    const int wv = tid >> 6, lane = tid & 63;
    const int l16 = lane & 15, quad = lane >> 4;
    const int mbase = wv * 16 + quad * 4;   // first of this lane's 4 C-rows

    f32x4 acc[8];
#pragma unroll
    for (int c = 0; c < 8; c++) acc[c] = (f32x4){0.f, 0.f, 0.f, 0.f};

#pragma unroll
    for (int kc = 0; kc < 4; ++kc) {
        bf16x8 af = *(const bf16x8*)&T[(wv * 16 + l16) * S + kc * 32 + quad * 8];
#pragma unroll
        for (int c = 0; c < 8; c++) {
            bf16x8 bfr = *(const bf16x8*)&Ws1[(((kc * 8 + c) * 64) + lane) * 8];
            acc[c] = MFMA16(af, bfr, acc[c]);
        }
    }
    __syncthreads();   // T becomes H

#pragma unroll
    for (int c = 0; c < 8; c++) {
        int col = c * 16 + l16;
        float bb = bls1[col];
#pragma unroll
        for (int q = 0; q < 4; q++)
            T[(mbase + q) * S + col] = (bf16_t)fmaxf(acc[c][q] + bb, 0.f);
    }
    __syncthreads();

#pragma unroll
    for (int c = 0; c < 8; c++) acc[c] = (f32x4){0.f, 0.f, 0.f, 0.f};

#pragma unroll
    for (int kc = 0; kc < 4; ++kc) {
        bf16x8 af = *(const bf16x8*)&T[(wv * 16 + l16) * S + kc * 32 + quad * 8];
#pragma unroll
        for (int c = 0; c < 8; c++) {
            bf16x8 bfr = *(const bf16x8*)&Ws2[(((kc * 8 + c) * 64) + lane) * 8];
            acc[c] = MFMA16(af, bfr, acc[c]);
        }
    }
    __syncthreads();   // T becomes Z

#pragma unroll
    for (int c = 0; c < 8; c++) {
        int col = c * 16 + l16;
        float bb = bls2[col];
        float s = 0.f, s2 = 0.f;
#pragma unroll
        for (int q = 0; q < 4; q++) {
            float v = acc[c][q] + bb;
            T[(mbase + q) * S + col] = (bf16_t)v;
            if (row0 + mbase + q < M) { s += v; s2 += v * v; }
        }
        s  += __shfl_xor(s, 16);  s  += __shfl_xor(s, 32);
        s2 += __shfl_xor(s2, 16); s2 += __shfl_xor(s2, 32);
        if (quad == 0) { atomicAdd(&bsum[col], s); atomicAdd(&bsq[col], s2); }
    }
    __syncthreads();

    for (int i = tid; i < 64 * 16; i += 256) {
        int row = i >> 4, seg = i & 15;
        long grow = row0 + row;
        if (grow < M)
            *(uint4*)&zout[grow * 128 + seg * 8] = *(const uint4*)&T[row * S + seg * 8];
    }
    if (tid < 128) {
        atomicAdd(&bn_sums[tid], bsum[tid]);
        atomicAdd(&bn_sums[128 + tid], bsq[tid]);
    }
}

// ---------------------------------------------------------------------------
// CSR gather aggregation: aggr[n] = h[n] + sum relu(h[src] + e). 1 wave/node,
// bf16 in/out, 2 channels/lane, 4-wide unrolled gather.
// ---------------------------------------------------------------------------
__global__ __launch_bounds__(256) void aggr_kernel(
    const bf16_t* __restrict__ h, const bf16_t* __restrict__ e,
    const int* __restrict__ rowptr, const int* __restrict__ srcp,
    bf16_t* __restrict__ aggr, int N)
{
    int wid = (int)(((long)blockIdx.x * 256 + threadIdx.x) >> 6);
    if (wid >= N) return;
    int lane = threadIdx.x & 63;
    bf16x2 hv = *(const bf16x2*)(h + (long)wid * 128 + lane * 2);
    float ax = (float)hv[0], ay = (float)hv[1];   // self term (eps=0)
    int beg = rowptr[wid], end = rowptr[wid + 1];
    int i = beg;
    for (; i + 3 < end; i += 4) {
        int s0 = srcp[i], s1 = srcp[i + 1], s2 = srcp[i + 2], s3 = srcp[i + 3];
        bf16x2 h0 = *(const bf16x2*)(h + (long)s0 * 128 + lane * 2);
        bf16x2 h1 = *(const bf16x2*)(h + (long)s1 * 128 + lane * 2);
        bf16x2 h2 = *(const bf16x2*)(h + (long)s2 * 128 + lane * 2);
        bf16x2 h3 = *(const bf16x2*)(h + (long)s3 * 128 + lane * 2);
        bf16x2 e0 = *(const bf16x2*)(e + (long)(i + 0) * 128 + lane * 2);
        bf16x2 e1 = *(const bf16x2*)(e + (long)(i + 1) * 128 + lane * 2);
        bf16x2 e2 = *(const bf16x2*)(e + (long)(i + 2) * 128 + lane * 2);
        bf16x2 e3 = *(const bf16x2*)(e + (long)(i + 3) * 128 + lane * 2);
        ax += fmaxf((float)h0[0] + (float)e0[0], 0.f);
        ay += fmaxf((float)h0[1] + (float)e0[1], 0.f);
        ax += fmaxf((float)h1[0] + (float)e1[0], 0.f);
        ay += fmaxf((float)h1[1] + (float)e1[1], 0.f);
        ax += fmaxf((float)h2[0] + (float)e2[0], 0.f);
        ay += fmaxf((float)h2[1] + (float)e2[1], 0.f);
        ax += fmaxf((float)h3[0] + (float)e3[0], 0.f);
        ay += fmaxf((float)h3[1] + (float)e3[1], 0.f);
    }
    for (; i < end; ++i) {
        int s0 = srcp[i];
        bf16x2 h0 = *(const bf16x2*)(h + (long)s0 * 128 + lane * 2);
        bf16x2 e0 = *(const bf16x2*)(e + (long)i * 128 + lane * 2);
        ax += fmaxf((float)h0[0] + (float)e0[0], 0.f);
        ay += fmaxf((float)h0[1] + (float)e0[1], 0.f);
    }
    bf16x2 o; o[0] = (bf16_t)ax; o[1] = (bf16_t)ay;
    *(bf16x2*)(aggr + (long)wid * 128 + lane * 2) = o;
}

// ---------------------------------------------------------------------------
__global__ void bn_fin_kernel(float* __restrict__ sums, const float* __restrict__ gamma,
                              const float* __restrict__ beta, float* __restrict__ scsh, int N)
{
    int c = threadIdx.x;
    float s  = sums[c];
    float sq = sums[128 + c];
    float mean = s / (float)N;
    float var  = sq / (float)N - mean * mean;
    float inv  = rsqrtf(var + 1e-5f);
    float sc   = gamma[c] * inv;
    scsh[c]       = sc;
    scsh[128 + c] = beta[c] - mean * sc;
    sums[c] = 0.f;
    sums[128 + c] = 0.f;
}

__global__ __launch_bounds__(256) void bn_apply_kernel(
    const bf16_t* __restrict__ z, const float* __restrict__ scsh,
    bf16_t* __restrict__ h, int total8)
{
    int idx = blockIdx.x * 256 + threadIdx.x;
    if (idx >= total8) return;
    long base = (long)idx * 8;
    int c0 = (int)(base & 127);
    bf16x8 zv = *(const bf16x8*)(z + base);
    bf16x8 hv;
#pragma unroll
    for (int j = 0; j < 8; j++)
        hv[j] = (bf16_t)fmaxf((float)zv[j] * scsh[c0 + j] + scsh[128 + c0 + j], 0.f);
    *(bf16x8*)(h + base) = hv;
}

// ---------------------------------------------------------------------------
__global__ __launch_bounds__(128) void pool_kernel(
    const bf16_t* __restrict__ h, const int* __restrict__ batch,
    float* __restrict__ gsum, float* __restrict__ cnt, int N)
{
    int c = threadIdx.x;
    int n0 = blockIdx.x * 256;
    int n1 = min(n0 + 256, N);
    float acc = 0.f;
    int cur = -1, rc = 0;
    for (int n = n0; n < n1; ++n) {
        int g = batch[n];
        if (g != cur) {
            if (cur >= 0) {
                atomicAdd(&gsum[(long)cur * 128 + c], acc);
                if (c == 0) atomicAdd(&cnt[cur], (float)rc);
            }
            cur = g; acc = 0.f; rc = 0;
        }
        acc += (float)h[(long)n * 128 + c];
        rc++;
    }
    if (cur >= 0) {
        atomicAdd(&gsum[(long)cur * 128 + c], acc);
        if (c == 0) atomicAdd(&cnt[cur], (float)rc);
    }
}

__global__ __launch_bounds__(128) void head_kernel(
    const float* __restrict__ gsum, const float* __restrict__ cnt,
    const float* __restrict__ ext_in,
    const float* __restrict__ ew1, const float* __restrict__ eb1,
    const float* __restrict__ ew2, const float* __restrict__ eb2,
    const float* __restrict__ rw1, const float* __restrict__ rb1,
    const float* __restrict__ rw2, const float* __restrict__ rb2,
    float* __restrict__ out)
{
    int g = blockIdx.x, c = threadIdx.x;
    __shared__ float sx[8];
    __shared__ float h1[128];
    __shared__ float comb[256];
    __shared__ float red[128];

    if (c < 8) sx[c] = ext_in[g * 8 + c];
    __syncthreads();
    float a = eb1[c];
#pragma unroll
    for (int k = 0; k < 8; k++) a += sx[k] * ew1[k * 128 + c];
    h1[c] = fmaxf(a, 0.f);
    __syncthreads();
    float b = eb2[c];
    for (int k = 0; k < 128; k++) b += h1[k] * ew2[k * 128 + c];
    comb[c]       = gsum[(long)g * 128 + c] / fmaxf(cnt[g], 1.0f);
    comb[128 + c] = b;
    __syncthreads();
    float r = rb1[c];
    for (int k = 0; k < 256; k++) r += comb[k] * rw1[k * 128 + c];
    r = fmaxf(r, 0.f);
    red[c] = r * rw2[c];
    __syncthreads();
    if (c == 0) {
        float s = rb2[0];
        for (int k = 0; k < 128; k++) s += red[k];
        out[g] = s;
    }
}

// ---------------------------------------------------------------------------
extern "C" void kernel_launch(void* const* d_in, const int* in_sizes, int n_in,
                              void* d_out, int out_size, void* d_ws, size_t ws_size,
                              hipStream_t stream)
{
    const float* x         = (const float*)d_in[0];
    const float* edge_attr = (const float*)d_in[1];
    const float* externals = (const float*)d_in[2];
    const float* node_w    = (const float*)d_in[3];
    const float* node_b    = (const float*)d_in[4];
    const float* ee_w1     = (const float*)d_in[5];
    const float* ee_b1     = (const float*)d_in[6];
    const float* ee_w2     = (const float*)d_in[7];
    const float* ee_b2     = (const float*)d_in[8];
    const float* conv_w1   = (const float*)d_in[9];
    const float* conv_b1   = (const float*)d_in[10];
    const float* conv_w2   = (const float*)d_in[11];
    const float* conv_b2   = (const float*)d_in[12];
    const float* bn_gamma  = (const float*)d_in[13];
    const float* bn_beta   = (const float*)d_in[14];
    const float* ext_w1    = (const float*)d_in[15];
    const float* ext_b1    = (const float*)d_in[16];
    const float* ext_w2    = (const float*)d_in[17];
    const float* ext_b2    = (const float*)d_in[18];
    const float* reg_w1    = (const float*)d_in[19];
    const float* reg_b1    = (const float*)d_in[20];
    const float* reg_w2    = (const float*)d_in[21];
    const float* reg_b2    = (const float*)d_in[22];
    const int* edge_index  = (const int*)d_in[23];
    const int* batch       = (const int*)d_in[24];

    const int N = in_sizes[0] / 32;
    const int E = in_sizes[1] / 16;
    const int G = in_sizes[2] / 8;
    const int NB = (N + 1023) / 1024;

    char* p = (char*)d_ws;
    auto alloc = [&](size_t bytes) -> void* {
        void* r = (void*)p;
        p += (bytes + 255) & ~(size_t)255;
        return r;
    };
    bf16_t* h       = (bf16_t*)alloc((size_t)N * 128 * 2);
    bf16_t* aggr    = (bf16_t*)alloc((size_t)N * 128 * 2);
    bf16_t* zbuf    = (bf16_t*)alloc((size_t)N * 128 * 2);
    bf16_t* ebuf    = (bf16_t*)alloc((size_t)E * 128 * 2);   // dst-sorted
    int*    deg     = (int*)alloc((size_t)N * 4);
    int*    rowptr  = (int*)alloc(((size_t)N + 1) * 4);
    int*    cursor  = (int*)alloc((size_t)N * 4);
    int*    partials= (int*)alloc((size_t)N * 4);
    int*    bsums   = (int*)alloc((size_t)NB * 4);
    int*    boff    = (int*)alloc((size_t)NB * 4);
    int*    srcp    = (int*)alloc((size_t)E * 4);
    int*    eorig   = (int*)alloc((size_t)E * 4);
    bf16_t* node_wt = (bf16_t*)alloc(128 * 32 * 2);
    bf16_t* ee_w1t  = (bf16_t*)alloc(128 * 32 * 2);
    bf16_t* ee_w2t  = (bf16_t*)alloc(128 * 128 * 2);
    bf16_t* cw1t    = (bf16_t*)alloc(3 * 128 * 128 * 2);
    bf16_t* cw2t    = (bf16_t*)alloc(3 * 128 * 128 * 2);
    float*  bn_sums = (float*)alloc(256 * 4);
    float*  scsh    = (float*)alloc(256 * 4);
    float*  gsum    = (float*)alloc((size_t)G * 128 * 4);
    float*  cnt     = (float*)alloc((size_t)G * 4);

    // --- CSR build (by dst) ---
    hipMemsetAsync(deg, 0, (size_t)N * 4, stream);
    hipMemsetAsync(bn_sums, 0, 256 * 4, stream);
    hist_kernel<<<(E + 255) / 256, 256, 0, stream>>>(edge_index, deg, E);
    scanA_kernel<<<NB, 256, 0, stream>>>(deg, partials, bsums, N);
    scanB_kernel<<<1, 256, 0, stream>>>(bsums, boff, rowptr, NB, N);
    scanC_kernel<<<(N + 255) / 256, 256, 0, stream>>>(partials, boff, rowptr, cursor, N);
    scatter_kernel<<<(E + 255) / 256, 256, 0, stream>>>(edge_index, cursor, srcp, eorig, E);

    // --- weight prep ---
    prep_w_kernel<<<16, 256, 0, stream>>>(node_w, node_wt, 32, 32);
    prep_w_kernel<<<16, 256, 0, stream>>>(ee_w1, ee_w1t, 16, 32);
    prep_w_kernel<<<64, 256, 0, stream>>>(ee_w2, ee_w2t, 128, 128);
    for (int l = 0; l < 3; l++) {
        prep_w_kernel<<<64, 256, 0, stream>>>(conv_w1 + l * 16384, cw1t + l * 16384, 128, 128);
        prep_w_kernel<<<64, 256, 0, stream>>>(conv_w2 + l * 16384, cw2t + l * 16384, 128, 128);
    }

    // --- node encoder ---
    node_enc_kernel<<<(N + 127) / 128, 256, 0, stream>>>(x, N, node_wt, node_b, h);

    // --- edge encoder, CSR-order compute, sequential write ---
    edge_mlp_kernel<<<(E + 127) / 128, 256, 0, stream>>>(
        edge_attr, E, ee_w1t, ee_b1, ee_w2t, ee_b2, eorig, ebuf);

    // --- GINE layers ---
    const int total8 = N * 128 / 8;
    for (int l = 0; l < 3; l++) {
        aggr_kernel<<<(N + 3) / 4, 256, 0, stream>>>(h, ebuf, rowptr, srcp, aggr, N);
        conv_fused_kernel<<<(N + 63) / 64, 256, 0, stream>>>(
            aggr, N, cw1t + l * 16384, conv_b1 + l * 128,
            cw2t + l * 16384, conv_b2 + l * 128, zbuf, bn_sums);
        bn_fin_kernel<<<1, 128, 0, stream>>>(bn_sums, bn_gamma + l * 128, bn_beta + l * 128, scsh, N);
        bn_apply_kernel<<<(total8 + 255) / 256, 256, 0, stream>>>(zbuf, scsh, h, total8);
    }

    // --- pooling + head ---
    hipMemsetAsync(gsum, 0, (size_t)G * 128 * 4, stream);
    hipMemsetAsync(cnt, 0, (size_t)G * 4, stream);
    pool_kernel<<<(N + 255) / 256, 128, 0, stream>>>(h, batch, gsum, cnt, N);
    head_kernel<<<G, 128, 0, stream>>>(gsum, cnt, externals,
                                       ext_w1, ext_b1, ext_w2, ext_b2,
                                       reg_w1, reg_b1, reg_w2, reg_b2,
                                       (float*)d_out);
}